// Round 1
// baseline (466.986 us; speedup 1.0000x reference)
//
#include <hip/hip_runtime.h>

// GCN 2-layer forward: out = softmax( A_norm @ relu(A_norm @ (x@W1) + b1) @ W2 + b2 )
// A_norm = D^-1/2 (A + I) D^-1/2, edges are col->row (row = target).
//
// Pipeline:
//   k_zero        : zero per-node counts
//   k_count       : counts[row[e]]++ (int atomics)
//   k_scan_block  : per-256-block exclusive scan of counts -> offsets, block totals
//   k_scan_sums   : single-block exclusive scan of block totals
//   k_finalize    : offsets += blockoff; cursor = offsets; dinv = rsqrt(counts+1)
//   k_scatter     : CSR bucket fill (sorted_col) via cursor atomics
//   k_gemm1       : h = x @ W1  (wave-per-row, W1 staged in LDS, shfl-broadcast x)
//   k_agg1        : wave-per-node: agg1 = sum norm*h[col] + self; relu(+b1);
//                   FUSED h2 = h1 @ W2 via 64-lane butterfly (h1 never materialized)
//   k_agg2        : thread-per-node: logits = sum norm*h2[col] + self + b2; softmax

__global__ void k_zero(int* __restrict__ a, int n) {
    int i = blockIdx.x * blockDim.x + threadIdx.x;
    if (i < n) a[i] = 0;
}

__global__ void k_count(const int* __restrict__ row, int* __restrict__ counts, int E) {
    int e = blockIdx.x * blockDim.x + threadIdx.x;
    if (e < E) atomicAdd(&counts[row[e]], 1);
}

__global__ void k_scan_block(const int* __restrict__ counts, int* __restrict__ offsets,
                             int* __restrict__ blocksums, int n) {
    __shared__ int tmp[256];
    int i = blockIdx.x * 256 + threadIdx.x;
    int v = (i < n) ? counts[i] : 0;
    tmp[threadIdx.x] = v;
    __syncthreads();
    for (int d = 1; d < 256; d <<= 1) {
        int t = (threadIdx.x >= (unsigned)d) ? tmp[threadIdx.x - d] : 0;
        __syncthreads();
        if (threadIdx.x >= (unsigned)d) tmp[threadIdx.x] += t;
        __syncthreads();
    }
    int incl = tmp[threadIdx.x];
    if (i < n) offsets[i] = incl - v;               // exclusive within block
    if (threadIdx.x == 255) blocksums[blockIdx.x] = incl;  // block total
}

__global__ void k_scan_sums(int* __restrict__ blocksums, int nb) {
    __shared__ int tmp[1024];
    int i = threadIdx.x;
    int v = (i < nb) ? blocksums[i] : 0;
    tmp[i] = v;
    __syncthreads();
    for (int d = 1; d < 1024; d <<= 1) {
        int t = (i >= (unsigned)d) ? tmp[i - d] : 0;
        __syncthreads();
        if (i >= (unsigned)d) tmp[i] += t;
        __syncthreads();
    }
    if (i < nb) blocksums[i] = tmp[i] - v;          // exclusive
}

__global__ void k_finalize(const int* __restrict__ counts, int* __restrict__ offsets,
                           const int* __restrict__ blocksums, int* __restrict__ cursor,
                           float* __restrict__ dinv, int n) {
    int i = blockIdx.x * blockDim.x + threadIdx.x;
    if (i >= n) return;
    int off = offsets[i] + blocksums[i >> 8];
    offsets[i] = off;
    cursor[i] = off;
    dinv[i] = rsqrtf((float)(counts[i] + 1));       // +1 = self-loop; deg >= 1 always
}

__global__ void k_scatter(const int* __restrict__ row, const int* __restrict__ col,
                          int* __restrict__ cursor, int* __restrict__ sorted_col, int E) {
    int e = blockIdx.x * blockDim.x + threadIdx.x;
    if (e >= E) return;
    int r = row[e];
    int pos = atomicAdd(&cursor[r], 1);
    sorted_col[pos] = col[e];
}

__global__ __launch_bounds__(256) void k_gemm1(const float* __restrict__ x,
                                               const float* __restrict__ W1,
                                               float* __restrict__ h, int N) {
    __shared__ float W1s[64 * 64];
    for (int i = threadIdx.x; i < 64 * 64; i += 256) W1s[i] = W1[i];
    __syncthreads();
    int lane = threadIdx.x & 63;
    int gw = (int)((blockIdx.x * 256 + threadIdx.x) >> 6);
    int stride = (int)((gridDim.x * 256) >> 6);
    for (int n = gw; n < N; n += stride) {
        float xv = x[(size_t)n * 64 + lane];
        float acc = 0.f;
#pragma unroll
        for (int k = 0; k < 64; ++k) {
            float xk = __shfl(xv, k, 64);
            // W1s[k*64+lane]: bank = lane%32 -> 2 lanes/bank, conflict-free
            acc = fmaf(xk, W1s[k * 64 + lane], acc);
        }
        h[(size_t)n * 64 + lane] = acc;
    }
}

// wave-per-node aggregation of layer 1, fused with relu(+b1) and the 64->2
// projection (h1 @ W2) so h1 is never written to memory.
__global__ __launch_bounds__(256) void k_agg1(const float* __restrict__ h,
                                              const int* __restrict__ offsets,
                                              const int* __restrict__ counts,
                                              const int* __restrict__ sorted_col,
                                              const float* __restrict__ dinv,
                                              const float* __restrict__ b1,
                                              const float* __restrict__ W2,
                                              float* __restrict__ h2, int N) {
    int lane = threadIdx.x & 63;
    int n = (int)((blockIdx.x * 256 + threadIdx.x) >> 6);
    if (n >= N) return;
    float dn = dinv[n];
    float acc = dn * dn * h[(size_t)n * 64 + lane];          // self-loop term
    int start = __builtin_amdgcn_readfirstlane(offsets[n]);
    int cnt   = __builtin_amdgcn_readfirstlane(counts[n]);
    for (int j = 0; j < cnt; ++j) {
        int c = __builtin_amdgcn_readfirstlane(sorted_col[start + j]);
        float w = dn * dinv[c];
        acc = fmaf(w, h[(size_t)c * 64 + lane], acc);        // 256B coalesced gather
    }
    float h1f = fmaxf(acc + b1[lane], 0.f);
    // fused h2 = h1 @ W2 : butterfly-reduce both class columns
    float p0 = h1f * W2[lane * 2 + 0];
    float p1 = h1f * W2[lane * 2 + 1];
#pragma unroll
    for (int off = 32; off >= 1; off >>= 1) {
        p0 += __shfl_xor(p0, off, 64);
        p1 += __shfl_xor(p1, off, 64);
    }
    if (lane == 0) h2[(size_t)n * 2 + 0] = p0;
    if (lane == 1) h2[(size_t)n * 2 + 1] = p1;
}

__global__ void k_agg2(const float* __restrict__ h2, const int* __restrict__ offsets,
                       const int* __restrict__ counts, const int* __restrict__ sorted_col,
                       const float* __restrict__ dinv, const float* __restrict__ b2,
                       float* __restrict__ out, int N) {
    int n = blockIdx.x * blockDim.x + threadIdx.x;
    if (n >= N) return;
    float dn = dinv[n];
    float a0 = dn * dn * h2[(size_t)n * 2 + 0];
    float a1 = dn * dn * h2[(size_t)n * 2 + 1];
    int start = offsets[n], cnt = counts[n];
    for (int j = 0; j < cnt; ++j) {
        int c = sorted_col[start + j];
        float w = dn * dinv[c];
        a0 = fmaf(w, h2[(size_t)c * 2 + 0], a0);
        a1 = fmaf(w, h2[(size_t)c * 2 + 1], a1);
    }
    float l0 = a0 + b2[0], l1 = a1 + b2[1];
    float m = fmaxf(l0, l1);
    float e0 = __expf(l0 - m), e1 = __expf(l1 - m);
    float inv = 1.0f / (e0 + e1);
    out[(size_t)n * 2 + 0] = e0 * inv;
    out[(size_t)n * 2 + 1] = e1 * inv;
}

extern "C" void kernel_launch(void* const* d_in, const int* in_sizes, int n_in,
                              void* d_out, int out_size, void* d_ws, size_t ws_size,
                              hipStream_t stream) {
    const float* x  = (const float*)d_in[0];
    const int*   ei = (const int*)d_in[1];
    const float* W1 = (const float*)d_in[2];
    const float* b1 = (const float*)d_in[3];
    const float* W2 = (const float*)d_in[4];
    const float* b2 = (const float*)d_in[5];
    float* out = (float*)d_out;

    const int N = in_sizes[0] / 64;     // 100000
    const int E = in_sizes[1] / 2;      // 1600000
    const int* row = ei;                // targets
    const int* col = ei + E;            // sources

    // workspace carve-up (256B aligned); total ~35 MB
    char* p = (char*)d_ws;
    auto alloc = [&](size_t bytes) -> void* {
        void* r = (void*)p;
        p += (bytes + 255) & ~(size_t)255;
        return r;
    };
    int*   counts    = (int*)alloc((size_t)N * 4);
    int*   offsets   = (int*)alloc((size_t)N * 4);
    int*   cursor    = (int*)alloc((size_t)N * 4);
    int*   blocksums = (int*)alloc(1024 * 4);
    float* dinv      = (float*)alloc((size_t)N * 4);
    int*   scol      = (int*)alloc((size_t)E * 4);
    float* h         = (float*)alloc((size_t)N * 64 * 4);
    float* h2        = (float*)alloc((size_t)N * 2 * 4);

    const int nbN = (N + 255) / 256;    // 391 (<=1024 for scan_sums)
    const int nbE = (E + 255) / 256;

    k_zero<<<nbN, 256, 0, stream>>>(counts, N);
    k_count<<<nbE, 256, 0, stream>>>(row, counts, E);
    k_scan_block<<<nbN, 256, 0, stream>>>(counts, offsets, blocksums, N);
    k_scan_sums<<<1, 1024, 0, stream>>>(blocksums, nbN);
    k_finalize<<<nbN, 256, 0, stream>>>(counts, offsets, blocksums, cursor, dinv, N);
    k_scatter<<<nbE, 256, 0, stream>>>(row, col, cursor, scol, E);
    k_gemm1<<<2048, 256, 0, stream>>>(x, W1, h, N);
    k_agg1<<<(N + 3) / 4, 256, 0, stream>>>(h, offsets, counts, scol, dinv, b1, W2, h2, N);
    k_agg2<<<nbN, 256, 0, stream>>>(h2, offsets, counts, scol, dinv, b2, out, N);
}

// Round 2
// 385.865 us; speedup vs baseline: 1.2102x; 1.2102x over previous
//
#include <hip/hip_runtime.h>

// GCN 2-layer forward: out = softmax( A_norm @ relu(A_norm @ (x@W1) + b1) @ W2 + b2 )
// A_norm = D^-1/2 (A + I) D^-1/2, edges are col->row (row = target).
//
// CSR build avoids random 4B scatter (R1: 105MB amplified writes, 130us) via
// two-phase binning: coarse buckets of 256 nodes (LDS-staged, coalesced pair
// writes), then per-bucket counting sort (writes land in one ~17KB region).

#define NBKT(n) (((n) + 255) >> 8)

__global__ void k_zero(int* __restrict__ a, int n) {
    int i = blockIdx.x * blockDim.x + threadIdx.x;
    if (i < n) a[i] = 0;
}

__global__ void k_count(const int* __restrict__ row, int* __restrict__ counts, int E) {
    int e = blockIdx.x * blockDim.x + threadIdx.x;
    if (e < E) atomicAdd(&counts[row[e]], 1);
}

__global__ void k_scan_block(const int* __restrict__ counts, int* __restrict__ offsets,
                             int* __restrict__ blocksums, int n) {
    __shared__ int tmp[256];
    int i = blockIdx.x * 256 + threadIdx.x;
    int v = (i < n) ? counts[i] : 0;
    tmp[threadIdx.x] = v;
    __syncthreads();
    for (int d = 1; d < 256; d <<= 1) {
        int t = (threadIdx.x >= (unsigned)d) ? tmp[threadIdx.x - d] : 0;
        __syncthreads();
        if (threadIdx.x >= (unsigned)d) tmp[threadIdx.x] += t;
        __syncthreads();
    }
    int incl = tmp[threadIdx.x];
    if (i < n) offsets[i] = incl - v;
    if (threadIdx.x == 255) blocksums[blockIdx.x] = incl;
}

__global__ void k_scan_sums(int* __restrict__ blocksums, int nb) {
    __shared__ int tmp[1024];
    int i = threadIdx.x;
    int v = (i < nb) ? blocksums[i] : 0;
    tmp[i] = v;
    __syncthreads();
    for (int d = 1; d < 1024; d <<= 1) {
        int t = (i >= (unsigned)d) ? tmp[i - d] : 0;
        __syncthreads();
        if (i >= (unsigned)d) tmp[i] += t;
        __syncthreads();
    }
    if (i < nb) blocksums[i] = tmp[i] - v;
}

// offsets += block base; dinv; bucket cursor/base = offsets at 256-node stride
__global__ void k_finalize(const int* __restrict__ counts, int* __restrict__ offsets,
                           const int* __restrict__ blocksums, float* __restrict__ dinv,
                           int* __restrict__ bcursor, int* __restrict__ bbase,
                           int n, int nb, int E) {
    int i = blockIdx.x * blockDim.x + threadIdx.x;
    if (i >= n) return;
    int off = offsets[i] + blocksums[i >> 8];
    offsets[i] = off;
    dinv[i] = rsqrtf((float)(counts[i] + 1));  // +1 self-loop
    if ((i & 255) == 0) { bcursor[i >> 8] = off; bbase[i >> 8] = off; }
    if (i == 0) bbase[nb] = E;
}

// Phase A: bin edges into 256-node buckets; LDS-staged so global writes are
// contiguous per-bucket runs (kills the 16x write amplification).
__global__ __launch_bounds__(256) void k_bin(const int* __restrict__ row,
                                             const int* __restrict__ col,
                                             int* __restrict__ bcursor,
                                             unsigned long long* __restrict__ pairbuf,
                                             int E, int nb) {
    __shared__ unsigned long long items[4096];
    __shared__ int cnt[392];
    __shared__ int start0[392];
    __shared__ int cursor[392];
    __shared__ int gbase[392];

    int base = blockIdx.x * 4096;
    int m = E - base; if (m > 4096) m = 4096;
    int tid = threadIdx.x;

    for (int t = tid; t < nb; t += 256) cnt[t] = 0;
    __syncthreads();
    // pass 1: count per bucket
    for (int i = tid; i < m; i += 256) {
        int r = row[base + i];
        atomicAdd(&cnt[r >> 8], 1);
    }
    __syncthreads();
    // exclusive scan of cnt[0..nb) by wave 0 (7 chunks of 64)
    if (tid < 64) {
        int lane = tid;
        int running = 0;
        for (int ch = 0; ch < 7; ++ch) {
            int idx = ch * 64 + lane;
            int v = (idx < nb) ? cnt[idx] : 0;
            int s = v;
#pragma unroll
            for (int off = 1; off < 64; off <<= 1) {
                int t = __shfl_up(s, off, 64);
                if (lane >= off) s += t;
            }
            if (idx < nb) { start0[idx] = running + s - v; cursor[idx] = running + s - v; }
            running += __shfl(s, 63, 64);
        }
    }
    __syncthreads();
    // pass 2: scatter into LDS grouped by bucket
    for (int i = tid; i < m; i += 256) {
        int r = row[base + i];
        int c = col[base + i];
        int b = r >> 8;
        int pos = atomicAdd(&cursor[b], 1);
        items[pos] = ((unsigned long long)(unsigned)r << 32) | (unsigned)c;
    }
    __syncthreads();
    // one global cursor grab per non-empty bucket
    for (int t = tid; t < nb; t += 256) {
        int cv = cnt[t];
        if (cv > 0) gbase[t] = atomicAdd(&bcursor[t], cv);
    }
    __syncthreads();
    // write out: contiguous runs per bucket
    for (int i = tid; i < m; i += 256) {
        unsigned long long it = items[i];
        int r = (int)(it >> 32);
        int b = r >> 8;
        pairbuf[gbase[b] + (i - start0[b])] = it;
    }
}

// Phase B: per-bucket counting sort -> final CSR sorted_col. All writes of a
// block land in one contiguous bucket region (full-line writebacks, 1 XCD).
__global__ __launch_bounds__(256) void k_sortbucket(const unsigned long long* __restrict__ pairbuf,
                                                    const int* __restrict__ bbase,
                                                    const int* __restrict__ offsets,
                                                    int* __restrict__ scol, int N) {
    __shared__ int cur[256];
    int b = blockIdx.x;
    int n0 = b << 8;
    int nn = N - n0; if (nn > 256) nn = 256;
    int tid = threadIdx.x;
    if (tid < nn) cur[tid] = offsets[n0 + tid];
    __syncthreads();
    int lo = bbase[b], hi = bbase[b + 1];
    for (int i = lo + tid; i < hi; i += 256) {
        unsigned long long it = pairbuf[i];
        int r = (int)(it >> 32);
        int c = (int)(it & 0xffffffffu);
        int pos = atomicAdd(&cur[r & 255], 1);
        scol[pos] = c;
    }
}

__global__ __launch_bounds__(256) void k_gemm1(const float* __restrict__ x,
                                               const float* __restrict__ W1,
                                               float* __restrict__ h, int N) {
    __shared__ float W1s[64 * 64];
    for (int i = threadIdx.x; i < 64 * 64; i += 256) W1s[i] = W1[i];
    __syncthreads();
    int lane = threadIdx.x & 63;
    int gw = (int)((blockIdx.x * 256 + threadIdx.x) >> 6);
    int stride = (int)((gridDim.x * 256) >> 6);
    for (int n = gw; n < N; n += stride) {
        float xv = x[(size_t)n * 64 + lane];
        float acc = 0.f;
#pragma unroll
        for (int k = 0; k < 64; ++k) {
            float xk = __shfl(xv, k, 64);
            acc = fmaf(xk, W1s[k * 64 + lane], acc);
        }
        h[(size_t)n * 64 + lane] = acc;
    }
}

// wave-per-node layer-1 aggregation, fused relu(+b1) and 64->2 projection.
// Lanes preload up to 64 (col, dinv) pairs in parallel; inner loop is
// shfl-broadcast + independent 256B h gathers (many loads in flight).
__global__ __launch_bounds__(256) void k_agg1(const float* __restrict__ h,
                                              const int* __restrict__ offsets,
                                              const int* __restrict__ counts,
                                              const int* __restrict__ sorted_col,
                                              const float* __restrict__ dinv,
                                              const float* __restrict__ b1,
                                              const float* __restrict__ W2,
                                              float* __restrict__ h2, int N) {
    int lane = threadIdx.x & 63;
    int n = (int)((blockIdx.x * 256 + threadIdx.x) >> 6);
    if (n >= N) return;
    float dn = dinv[n];
    float acc = dn * dn * h[(size_t)n * 64 + lane];          // self-loop
    int start = __builtin_amdgcn_readfirstlane(offsets[n]);
    int cnt   = __builtin_amdgcn_readfirstlane(counts[n]);
    for (int jj = 0; jj < cnt; jj += 64) {
        int rem = cnt - jj;
        int m = rem < 64 ? rem : 64;
        int c = 0; float w = 0.f;
        if (jj + lane < cnt) { c = sorted_col[start + jj + lane]; w = dinv[c]; }
        for (int j = 0; j < m; ++j) {
            int cj = __shfl(c, j, 64);
            float wj = __shfl(w, j, 64);
            acc = fmaf(dn * wj, h[(size_t)cj * 64 + lane], acc);
        }
    }
    float h1f = fmaxf(acc + b1[lane], 0.f);
    float p0 = h1f * W2[lane * 2 + 0];
    float p1 = h1f * W2[lane * 2 + 1];
#pragma unroll
    for (int off = 32; off >= 1; off >>= 1) {
        p0 += __shfl_xor(p0, off, 64);
        p1 += __shfl_xor(p1, off, 64);
    }
    if (lane == 0) h2[(size_t)n * 2 + 0] = p0;
    if (lane == 1) h2[(size_t)n * 2 + 1] = p1;
}

__global__ void k_agg2(const float* __restrict__ h2, const int* __restrict__ offsets,
                       const int* __restrict__ counts, const int* __restrict__ sorted_col,
                       const float* __restrict__ dinv, const float* __restrict__ b2,
                       float* __restrict__ out, int N) {
    int n = blockIdx.x * blockDim.x + threadIdx.x;
    if (n >= N) return;
    float dn = dinv[n];
    float a0 = dn * dn * h2[(size_t)n * 2 + 0];
    float a1 = dn * dn * h2[(size_t)n * 2 + 1];
    int start = offsets[n], cnt = counts[n];
    for (int j = 0; j < cnt; ++j) {
        int c = sorted_col[start + j];
        float w = dn * dinv[c];
        a0 = fmaf(w, h2[(size_t)c * 2 + 0], a0);
        a1 = fmaf(w, h2[(size_t)c * 2 + 1], a1);
    }
    float l0 = a0 + b2[0], l1 = a1 + b2[1];
    float m = fmaxf(l0, l1);
    float e0 = __expf(l0 - m), e1 = __expf(l1 - m);
    float inv = 1.0f / (e0 + e1);
    out[(size_t)n * 2 + 0] = e0 * inv;
    out[(size_t)n * 2 + 1] = e1 * inv;
}

extern "C" void kernel_launch(void* const* d_in, const int* in_sizes, int n_in,
                              void* d_out, int out_size, void* d_ws, size_t ws_size,
                              hipStream_t stream) {
    const float* x  = (const float*)d_in[0];
    const int*   ei = (const int*)d_in[1];
    const float* W1 = (const float*)d_in[2];
    const float* b1 = (const float*)d_in[3];
    const float* W2 = (const float*)d_in[4];
    const float* b2 = (const float*)d_in[5];
    float* out = (float*)d_out;

    const int N = in_sizes[0] / 64;     // 100000
    const int E = in_sizes[1] / 2;      // 1600000
    const int nb = NBKT(N);             // 391
    const int* row = ei;                // targets
    const int* col = ei + E;            // sources

    char* p = (char*)d_ws;
    auto alloc = [&](size_t bytes) -> void* {
        void* r = (void*)p;
        p += (bytes + 255) & ~(size_t)255;
        return r;
    };
    int*   counts    = (int*)alloc((size_t)N * 4);
    int*   offsets   = (int*)alloc((size_t)N * 4);
    int*   blocksums = (int*)alloc(1024 * 4);
    float* dinv      = (float*)alloc((size_t)N * 4);
    int*   bcursor   = (int*)alloc((size_t)(nb + 1) * 4);
    int*   bbase     = (int*)alloc((size_t)(nb + 1) * 4);
    unsigned long long* pairbuf = (unsigned long long*)alloc((size_t)E * 8);
    int*   scol      = (int*)alloc((size_t)E * 4);
    float* h         = (float*)alloc((size_t)N * 64 * 4);
    float* h2        = (float*)alloc((size_t)N * 2 * 4);

    const int nbN = (N + 255) / 256;    // 391
    const int nbE = (E + 255) / 256;
    const int nBin = (E + 4095) / 4096; // 391

    k_zero<<<nbN, 256, 0, stream>>>(counts, N);
    k_count<<<nbE, 256, 0, stream>>>(row, counts, E);
    k_scan_block<<<nbN, 256, 0, stream>>>(counts, offsets, blocksums, N);
    k_scan_sums<<<1, 1024, 0, stream>>>(blocksums, nbN);
    k_finalize<<<nbN, 256, 0, stream>>>(counts, offsets, blocksums, dinv, bcursor, bbase, N, nb, E);
    k_bin<<<nBin, 256, 0, stream>>>(row, col, bcursor, pairbuf, E, nb);
    k_sortbucket<<<nb, 256, 0, stream>>>(pairbuf, bbase, offsets, scol, N);
    k_gemm1<<<2048, 256, 0, stream>>>(x, W1, h, N);
    k_agg1<<<(N + 3) / 4, 256, 0, stream>>>(h, offsets, counts, scol, dinv, b1, W2, h2, N);
    k_agg2<<<nbN, 256, 0, stream>>>(h2, offsets, counts, scol, dinv, b2, out, N);
}

// Round 3
// 300.991 us; speedup vs baseline: 1.5515x; 1.2820x over previous
//
#include <hip/hip_runtime.h>
#include <hip/hip_fp16.h>

// GCN 2-layer forward: out = softmax( A_norm @ relu(A_norm @ (x@W1) + b1) @ W2 + b2 )
// A_norm = D^-1/2 (A + I) D^-1/2, edges are col->row (row = target).
//
// R2: agg1 was top (107us, FETCH 195MB) — fp32 h gather thrashes per-XCD L2,
// plus 2 ds-shfl/edge and 64 ds-shfl/node in gemm1. This round:
//  - h stored fp16 PRE-SCALED by dinv (hp[c] = fp16(dinv[c]*h[c])): edge term
//    becomes a pure add (dn factors out of the whole sum), 128B/edge gather,
//    12.8MB table fits aggregate L2.
//  - agg1 processes 2 edges/wave-iter (32 lanes x half2 per edge) via
//    variable-src shfl; invalid lanes gather a dedicated zero row (row N).
//  - gemm1: lane = out-feature, W1 column in 64 VGPRs, x row via wave-uniform
//    (scalar) loads — zero LDS/ds ops.
//  - h2 stored pre-scaled as float2; agg2 drops its dinv gather.

#define NBKT(n) (((n) + 255) >> 8)

__global__ void k_zero(int* __restrict__ a, int n) {
    int i = blockIdx.x * blockDim.x + threadIdx.x;
    if (i < n) a[i] = 0;
}

__global__ void k_count(const int* __restrict__ row, int* __restrict__ counts, int E) {
    int e = blockIdx.x * blockDim.x + threadIdx.x;
    if (e < E) atomicAdd(&counts[row[e]], 1);
}

__global__ void k_scan_block(const int* __restrict__ counts, int* __restrict__ offsets,
                             int* __restrict__ blocksums, int n) {
    __shared__ int tmp[256];
    int i = blockIdx.x * 256 + threadIdx.x;
    int v = (i < n) ? counts[i] : 0;
    tmp[threadIdx.x] = v;
    __syncthreads();
    for (int d = 1; d < 256; d <<= 1) {
        int t = (threadIdx.x >= (unsigned)d) ? tmp[threadIdx.x - d] : 0;
        __syncthreads();
        if (threadIdx.x >= (unsigned)d) tmp[threadIdx.x] += t;
        __syncthreads();
    }
    int incl = tmp[threadIdx.x];
    if (i < n) offsets[i] = incl - v;
    if (threadIdx.x == 255) blocksums[blockIdx.x] = incl;
}

__global__ void k_scan_sums(int* __restrict__ blocksums, int nb) {
    __shared__ int tmp[1024];
    int i = threadIdx.x;
    int v = (i < nb) ? blocksums[i] : 0;
    tmp[i] = v;
    __syncthreads();
    for (int d = 1; d < 1024; d <<= 1) {
        int t = (i >= (unsigned)d) ? tmp[i - d] : 0;
        __syncthreads();
        if (i >= (unsigned)d) tmp[i] += t;
        __syncthreads();
    }
    if (i < nb) blocksums[i] = tmp[i] - v;
}

// offsets += block base; dinv; bucket cursors; zero row N of hp (128B)
__global__ void k_finalize(const int* __restrict__ counts, int* __restrict__ offsets,
                           const int* __restrict__ blocksums, float* __restrict__ dinv,
                           int* __restrict__ bcursor, int* __restrict__ bbase,
                           __half* __restrict__ hp, int n, int nb, int E) {
    int i = blockIdx.x * blockDim.x + threadIdx.x;
    if (i >= n) return;
    int off = offsets[i] + blocksums[i >> 8];
    offsets[i] = off;
    dinv[i] = rsqrtf((float)(counts[i] + 1));  // +1 self-loop
    if ((i & 255) == 0) { bcursor[i >> 8] = off; bbase[i >> 8] = off; }
    if (i == 0) bbase[nb] = E;
    if (i < 32) ((int*)(hp + (size_t)n * 64))[i] = 0;   // zero row N
}

// Phase A: bin edges into 256-node buckets (LDS-staged, coalesced pair runs)
__global__ __launch_bounds__(256) void k_bin(const int* __restrict__ row,
                                             const int* __restrict__ col,
                                             int* __restrict__ bcursor,
                                             unsigned long long* __restrict__ pairbuf,
                                             int E, int nb) {
    __shared__ unsigned long long items[4096];
    __shared__ int cnt[392];
    __shared__ int start0[392];
    __shared__ int cursor[392];
    __shared__ int gbase[392];

    int base = blockIdx.x * 4096;
    int m = E - base; if (m > 4096) m = 4096;
    int tid = threadIdx.x;

    for (int t = tid; t < nb; t += 256) cnt[t] = 0;
    __syncthreads();
    for (int i = tid; i < m; i += 256) {
        int r = row[base + i];
        atomicAdd(&cnt[r >> 8], 1);
    }
    __syncthreads();
    if (tid < 64) {
        int lane = tid;
        int running = 0;
        for (int ch = 0; ch < 7; ++ch) {
            int idx = ch * 64 + lane;
            int v = (idx < nb) ? cnt[idx] : 0;
            int s = v;
#pragma unroll
            for (int off = 1; off < 64; off <<= 1) {
                int t = __shfl_up(s, off, 64);
                if (lane >= off) s += t;
            }
            if (idx < nb) { start0[idx] = running + s - v; cursor[idx] = running + s - v; }
            running += __shfl(s, 63, 64);
        }
    }
    __syncthreads();
    for (int i = tid; i < m; i += 256) {
        int r = row[base + i];
        int c = col[base + i];
        int b = r >> 8;
        int pos = atomicAdd(&cursor[b], 1);
        items[pos] = ((unsigned long long)(unsigned)r << 32) | (unsigned)c;
    }
    __syncthreads();
    for (int t = tid; t < nb; t += 256) {
        int cv = cnt[t];
        if (cv > 0) gbase[t] = atomicAdd(&bcursor[t], cv);
    }
    __syncthreads();
    for (int i = tid; i < m; i += 256) {
        unsigned long long it = items[i];
        int r = (int)(it >> 32);
        int b = r >> 8;
        pairbuf[gbase[b] + (i - start0[b])] = it;
    }
}

// Phase B: per-bucket counting sort -> final CSR sorted_col
__global__ __launch_bounds__(256) void k_sortbucket(const unsigned long long* __restrict__ pairbuf,
                                                    const int* __restrict__ bbase,
                                                    const int* __restrict__ offsets,
                                                    int* __restrict__ scol, int N) {
    __shared__ int cur[256];
    int b = blockIdx.x;
    int n0 = b << 8;
    int nn = N - n0; if (nn > 256) nn = 256;
    int tid = threadIdx.x;
    if (tid < nn) cur[tid] = offsets[n0 + tid];
    __syncthreads();
    int lo = bbase[b], hi = bbase[b + 1];
    for (int i = lo + tid; i < hi; i += 256) {
        unsigned long long it = pairbuf[i];
        int r = (int)(it >> 32);
        int c = (int)(it & 0xffffffffu);
        int pos = atomicAdd(&cur[r & 255], 1);
        scol[pos] = c;
    }
}

// h_pre[n][f] = fp16( dinv[n] * (x @ W1)[n][f] ), lane = feature f.
// W1 column lives in 64 VGPRs (amortized over grid-stride); x row address is
// wave-uniform -> scalar/broadcast loads. No LDS, no shfl.
__global__ __launch_bounds__(256) void k_gemm1(const float* __restrict__ x,
                                               const float* __restrict__ W1,
                                               const float* __restrict__ dinv,
                                               __half* __restrict__ hp, int N) {
    int lane = threadIdx.x & 63;
    float w1c[64];
#pragma unroll
    for (int k = 0; k < 64; ++k) w1c[k] = W1[k * 64 + lane];
    int wv = (int)((blockIdx.x * 256 + threadIdx.x) >> 6);
    int nw = (int)((gridDim.x * 256) >> 6);
    for (int n = wv; n < N; n += nw) {
        int nu = __builtin_amdgcn_readfirstlane(n);
        const float* xr = x + (size_t)nu * 64;
        float a0 = 0.f, a1 = 0.f, a2 = 0.f, a3 = 0.f;
#pragma unroll
        for (int k = 0; k < 64; k += 4) {
            a0 = fmaf(xr[k + 0], w1c[k + 0], a0);
            a1 = fmaf(xr[k + 1], w1c[k + 1], a1);
            a2 = fmaf(xr[k + 2], w1c[k + 2], a2);
            a3 = fmaf(xr[k + 3], w1c[k + 3], a3);
        }
        float acc = (a0 + a1) + (a2 + a3);
        hp[(size_t)nu * 64 + lane] = __float2half(dinv[nu] * acc);
    }
}

// Layer-1 aggregation + relu(+b1) + 64->2 projection, fused.
// Wave = 1 node; lane = (half, feature-pair): 32 lanes gather one edge's 64
// fp16 features as half2; two edges in flight per iteration.
__global__ __launch_bounds__(256) void k_agg1(const __half* __restrict__ hp,
                                              const int* __restrict__ offsets,
                                              const int* __restrict__ counts,
                                              const int* __restrict__ sorted_col,
                                              const float* __restrict__ dinv,
                                              const float* __restrict__ b1,
                                              const float* __restrict__ W2,
                                              float2* __restrict__ h2p, int N) {
    int lane = threadIdx.x & 63;
    int half = lane >> 5;
    int fl = lane & 31;                 // features 2fl, 2fl+1
    int n = (int)((blockIdx.x * 256 + threadIdx.x) >> 6);
    if (n >= N) return;
    const __half2* hp2 = (const __half2*)hp;
    float accx = 0.f, accy = 0.f;
    if (half == 0) {                    // self term (counted once)
        float2 s = __half22float2(hp2[(size_t)n * 32 + fl]);
        accx = s.x; accy = s.y;
    }
    int start = __builtin_amdgcn_readfirstlane(offsets[n]);
    int cnt   = __builtin_amdgcn_readfirstlane(counts[n]);
    for (int jj = 0; jj < cnt; jj += 64) {
        int c = N;                      // zero row for invalid lanes
        if (jj + lane < cnt) c = sorted_col[start + jj + lane];
        int m = cnt - jj; if (m > 64) m = 64;
        int pairs = (m + 1) >> 1;
        for (int j = 0; j < pairs; ++j) {
            int cj = __shfl(c, 2 * j + half, 64);   // invalid src holds N -> +0
            float2 v = __half22float2(hp2[(size_t)cj * 32 + fl]);
            accx += v.x; accy += v.y;
        }
    }
    // combine the two halves (feature pair fl summed over ALL edges)
    accx += __shfl_xor(accx, 32, 64);
    accy += __shfl_xor(accy, 32, 64);
    float dn = dinv[n];
    float2 bb = ((const float2*)b1)[fl];
    float h1x = fmaxf(fmaf(dn, accx, bb.x), 0.f);
    float h1y = fmaxf(fmaf(dn, accy, bb.y), 0.f);
    float2 w0 = ((const float2*)W2)[2 * fl];        // W2[2fl][0..1]
    float2 w1 = ((const float2*)W2)[2 * fl + 1];    // W2[2fl+1][0..1]
    float p0 = fmaf(h1x, w0.x, h1y * w1.x);
    float p1 = fmaf(h1x, w0.y, h1y * w1.y);
    // both halves identical now; butterfly within a half
#pragma unroll
    for (int off = 16; off >= 1; off >>= 1) {
        p0 += __shfl_xor(p0, off, 64);
        p1 += __shfl_xor(p1, off, 64);
    }
    if (lane == 0) h2p[n] = make_float2(dn * p0, dn * p1);  // pre-scaled
}

__global__ void k_agg2(const float2* __restrict__ h2p, const int* __restrict__ offsets,
                       const int* __restrict__ counts, const int* __restrict__ sorted_col,
                       const float* __restrict__ dinv, const float* __restrict__ b2,
                       float* __restrict__ out, int N) {
    int n = blockIdx.x * blockDim.x + threadIdx.x;
    if (n >= N) return;
    float2 s = h2p[n];                  // self term (pre-scaled)
    float a0 = s.x, a1 = s.y;
    int start = offsets[n], cnt = counts[n];
    for (int j = 0; j < cnt; ++j) {
        int c = sorted_col[start + j];
        float2 v = h2p[c];
        a0 += v.x; a1 += v.y;
    }
    float dn = dinv[n];
    float l0 = fmaf(dn, a0, b2[0]), l1 = fmaf(dn, a1, b2[1]);
    float m = fmaxf(l0, l1);
    float e0 = __expf(l0 - m), e1 = __expf(l1 - m);
    float inv = 1.0f / (e0 + e1);
    out[(size_t)n * 2 + 0] = e0 * inv;
    out[(size_t)n * 2 + 1] = e1 * inv;
}

extern "C" void kernel_launch(void* const* d_in, const int* in_sizes, int n_in,
                              void* d_out, int out_size, void* d_ws, size_t ws_size,
                              hipStream_t stream) {
    const float* x  = (const float*)d_in[0];
    const int*   ei = (const int*)d_in[1];
    const float* W1 = (const float*)d_in[2];
    const float* b1 = (const float*)d_in[3];
    const float* W2 = (const float*)d_in[4];
    const float* b2 = (const float*)d_in[5];
    float* out = (float*)d_out;

    const int N = in_sizes[0] / 64;     // 100000
    const int E = in_sizes[1] / 2;      // 1600000
    const int nb = NBKT(N);             // 391
    const int* row = ei;
    const int* col = ei + E;

    char* p = (char*)d_ws;
    auto alloc = [&](size_t bytes) -> void* {
        void* r = (void*)p;
        p += (bytes + 255) & ~(size_t)255;
        return r;
    };
    int*   counts    = (int*)alloc((size_t)N * 4);
    int*   offsets   = (int*)alloc((size_t)N * 4);
    int*   blocksums = (int*)alloc(1024 * 4);
    float* dinv      = (float*)alloc((size_t)N * 4);
    int*   bcursor   = (int*)alloc((size_t)(nb + 1) * 4);
    int*   bbase     = (int*)alloc((size_t)(nb + 1) * 4);
    unsigned long long* pairbuf = (unsigned long long*)alloc((size_t)E * 8);
    int*   scol      = (int*)alloc((size_t)E * 4);
    __half* hp       = (__half*)alloc((size_t)(N + 1) * 64 * 2);  // +1 zero row
    float2* h2p      = (float2*)alloc((size_t)N * 8);

    const int nbN = (N + 255) / 256;    // 391
    const int nbE = (E + 255) / 256;
    const int nBin = (E + 4095) / 4096; // 391

    k_zero<<<nbN, 256, 0, stream>>>(counts, N);
    k_count<<<nbE, 256, 0, stream>>>(row, counts, E);
    k_scan_block<<<nbN, 256, 0, stream>>>(counts, offsets, blocksums, N);
    k_scan_sums<<<1, 1024, 0, stream>>>(blocksums, nbN);
    k_finalize<<<nbN, 256, 0, stream>>>(counts, offsets, blocksums, dinv, bcursor, bbase, hp, N, nb, E);
    k_bin<<<nBin, 256, 0, stream>>>(row, col, bcursor, pairbuf, E, nb);
    k_sortbucket<<<nb, 256, 0, stream>>>(pairbuf, bbase, offsets, scol, N);
    k_gemm1<<<512, 256, 0, stream>>>(x, W1, dinv, hp, N);
    k_agg1<<<(N + 3) / 4, 256, 0, stream>>>(hp, offsets, counts, scol, dinv, b1, W2, h2p, N);
    k_agg2<<<nbN, 256, 0, stream>>>(h2p, offsets, counts, scol, dinv, b2, out, N);
}

// Round 5
// 228.962 us; speedup vs baseline: 2.0396x; 1.3146x over previous
//
#include <hip/hip_runtime.h>
#include <hip/hip_fp16.h>

// GCN 2-layer forward: out = softmax( A_norm @ relu(A_norm @ (x@W1) + b1) @ W2 + b2 )
// A_norm = D^-1/2 (A + I) D^-1/2, edges are col->row (row = target).
//
// R4 -> R5: R4 aborted — bcnt/relcur were separate 256B-aligned allocs but a
// single memset covered only part of relcur (rest stayed 0xAA poison ->
// gbase garbage -> pairbuf OOB). Fix: one contiguous block, exact memset.
// Design otherwise identical to R4:
//  - agg1: 8 edges per wave-iter (8 lanes x dwordx4 per edge), half2 pk-add.
//  - CSR build in 3 kernels (bucket hist -> bin -> per-bucket sort).
//  - agg2: 16 lanes per node.

#define NBKT(n) (((n) + 255) >> 8)

// ---- 1. per-bucket histogram of row>>8 (+ zero hp row N) -------------------
__global__ __launch_bounds__(256) void k_bucketcount(const int* __restrict__ row,
                                                     int* __restrict__ bcnt,
                                                     __half* __restrict__ hp,
                                                     int E, int nb, int N) {
    __shared__ int cnt[392];
    int tid = threadIdx.x;
    int base = blockIdx.x * 4096;
    int m = E - base; if (m > 4096) m = 4096;
    for (int t = tid; t < nb; t += 256) cnt[t] = 0;
    __syncthreads();
    for (int i = tid; i < m; i += 256) atomicAdd(&cnt[row[base + i] >> 8], 1);
    __syncthreads();
    for (int t = tid; t < nb; t += 256) {
        int v = cnt[t];
        if (v > 0) atomicAdd(&bcnt[t], v);
    }
    if (blockIdx.x == 0 && tid < 32) ((int*)(hp + (size_t)N * 64))[tid] = 0;
}

// ---- 2. bin edges into 256-node buckets (coalesced pair runs) --------------
__global__ __launch_bounds__(256) void k_bin(const int* __restrict__ row,
                                             const int* __restrict__ col,
                                             const int* __restrict__ bcnt,
                                             int* __restrict__ relcur,
                                             unsigned long long* __restrict__ pairbuf,
                                             int E, int nb) {
    __shared__ unsigned long long items[4096];
    __shared__ int cnt[392];     // tile-local bucket counts
    __shared__ int start0[392];  // tile-local bucket starts
    __shared__ int cursor[392];
    __shared__ int gb[392];      // global bucket bases (scan of bcnt)
    __shared__ int gbase[392];

    int tid = threadIdx.x;
    int base = blockIdx.x * 4096;
    int m = E - base; if (m > 4096) m = 4096;

    for (int t = tid; t < nb; t += 256) cnt[t] = 0;
    __syncthreads();
    for (int i = tid; i < m; i += 256) atomicAdd(&cnt[row[base + i] >> 8], 1);
    __syncthreads();
    // two parallel wave-scans: wave0 scans tile counts, wave1 scans global bcnt
    if (tid < 64) {
        int lane = tid, running = 0;
        for (int ch = 0; ch < 7; ++ch) {
            int idx = ch * 64 + lane;
            int v = (idx < nb) ? cnt[idx] : 0;
            int s = v;
#pragma unroll
            for (int off = 1; off < 64; off <<= 1) {
                int t = __shfl_up(s, off, 64);
                if (lane >= off) s += t;
            }
            if (idx < nb) { start0[idx] = running + s - v; cursor[idx] = running + s - v; }
            running += __shfl(s, 63, 64);
        }
    } else if (tid < 128) {
        int lane = tid - 64, running = 0;
        for (int ch = 0; ch < 7; ++ch) {
            int idx = ch * 64 + lane;
            int v = (idx < nb) ? bcnt[idx] : 0;
            int s = v;
#pragma unroll
            for (int off = 1; off < 64; off <<= 1) {
                int t = __shfl_up(s, off, 64);
                if (lane >= off) s += t;
            }
            if (idx < nb) gb[idx] = running + s - v;
            running += __shfl(s, 63, 64);
        }
    }
    __syncthreads();
    for (int i = tid; i < m; i += 256) {
        int r = row[base + i];
        int c = col[base + i];
        int pos = atomicAdd(&cursor[r >> 8], 1);
        items[pos] = ((unsigned long long)(unsigned)r << 32) | (unsigned)c;
    }
    __syncthreads();
    for (int t = tid; t < nb; t += 256) {
        int cv = cnt[t];
        if (cv > 0) gbase[t] = gb[t] + atomicAdd(&relcur[t], cv);
    }
    __syncthreads();
    for (int i = tid; i < m; i += 256) {
        unsigned long long it = items[i];
        int b = ((int)(it >> 32)) >> 8;
        pairbuf[gbase[b] + (i - start0[b])] = it;
    }
}

// ---- 3. per-bucket counting sort -> scol, offsets, dinv --------------------
__global__ __launch_bounds__(256) void k_sortnode(const unsigned long long* __restrict__ pairbuf,
                                                  const int* __restrict__ bcnt,
                                                  int* __restrict__ scol,
                                                  int* __restrict__ offsets,
                                                  float* __restrict__ dinv,
                                                  int N, int E) {
    __shared__ int ps[256];
    __shared__ int cnt[256];
    __shared__ int tmp[256];
    __shared__ int cur[256];
    int b = blockIdx.x;
    int tid = threadIdx.x;
    // lo = sum(bcnt[0..b))
    int v = (tid < b) ? bcnt[tid] : 0;
    if (tid + 256 < b) v += bcnt[tid + 256];
    ps[tid] = v;
    __syncthreads();
    for (int s = 128; s >= 1; s >>= 1) {
        if (tid < s) ps[tid] += ps[tid + s];
        __syncthreads();
    }
    int lo = ps[0];
    int hi = lo + bcnt[b];
    cnt[tid] = 0;
    __syncthreads();
    for (int i = lo + tid; i < hi; i += 256)
        atomicAdd(&cnt[(int)(pairbuf[i] >> 32) & 255], 1);
    __syncthreads();
    // exclusive scan of cnt
    int cv = cnt[tid];
    tmp[tid] = cv;
    __syncthreads();
    for (int d = 1; d < 256; d <<= 1) {
        int t = (tid >= (unsigned)d) ? tmp[tid - d] : 0;
        __syncthreads();
        if (tid >= (unsigned)d) tmp[tid] += t;
        __syncthreads();
    }
    int excl = tmp[tid] - cv;
    int n = (b << 8) + tid;
    if (n < N) {
        offsets[n] = lo + excl;
        dinv[n] = rsqrtf((float)(cv + 1));  // +1 self-loop
    }
    cur[tid] = lo + excl;
    if (b == 0 && tid == 0) offsets[N] = E;
    __syncthreads();
    for (int i = lo + tid; i < hi; i += 256) {
        unsigned long long it = pairbuf[i];
        int r = (int)(it >> 32);
        int pos = atomicAdd(&cur[r & 255], 1);
        scol[pos] = (int)(it & 0xffffffffu);
    }
}

// ---- 4. hp[n][f] = fp16( dinv[n] * (x @ W1)[n][f] ) ------------------------
__global__ __launch_bounds__(256) void k_gemm1(const float* __restrict__ x,
                                               const float* __restrict__ W1,
                                               const float* __restrict__ dinv,
                                               __half* __restrict__ hp, int N) {
    int lane = threadIdx.x & 63;
    float w1c[64];
#pragma unroll
    for (int k = 0; k < 64; ++k) w1c[k] = W1[k * 64 + lane];
    int wv = (int)((blockIdx.x * 256 + threadIdx.x) >> 6);
    int nw = (int)((gridDim.x * 256) >> 6);
    for (int n = wv; n < N; n += nw) {
        int nu = __builtin_amdgcn_readfirstlane(n);
        const float* xr = x + (size_t)nu * 64;
        float a0 = 0.f, a1 = 0.f, a2 = 0.f, a3 = 0.f;
#pragma unroll
        for (int k = 0; k < 64; k += 4) {
            a0 = fmaf(xr[k + 0], w1c[k + 0], a0);
            a1 = fmaf(xr[k + 1], w1c[k + 1], a1);
            a2 = fmaf(xr[k + 2], w1c[k + 2], a2);
            a3 = fmaf(xr[k + 3], w1c[k + 3], a3);
        }
        float acc = (a0 + a1) + (a2 + a3);
        hp[(size_t)nu * 64 + lane] = __float2half(dinv[nu] * acc);
    }
}

// ---- 5. layer-1 agg + relu(+b1) + 64->2 projection, fused ------------------
// Wave = 1 node. lane = (eslot = lane>>3, chunk = lane&7): 8 lanes x 16B cover
// one edge's 128B feature row; 8 edges in flight per iteration.
__global__ __launch_bounds__(256) void k_agg1(const __half* __restrict__ hp,
                                              const int* __restrict__ offsets,
                                              const int* __restrict__ sorted_col,
                                              const float* __restrict__ dinv,
                                              const float* __restrict__ b1,
                                              const float* __restrict__ W2,
                                              float2* __restrict__ h2p, int N) {
    int lane = threadIdx.x & 63;
    int eslot = lane >> 3;
    int chunk = lane & 7;           // features 8*chunk .. 8*chunk+7
    int n = (int)((blockIdx.x * 256 + threadIdx.x) >> 6);
    if (n >= N) return;
    const float4* hp4 = (const float4*)hp;   // row stride = 8 float4
    __half2 acc[4];
#pragma unroll
    for (int k = 0; k < 4; ++k) acc[k] = __half2half2(__float2half(0.f));
    int start = __builtin_amdgcn_readfirstlane(offsets[n]);
    int end   = __builtin_amdgcn_readfirstlane(offsets[n + 1]);
    int cnt = end - start;
    if (eslot == 0) {               // self term once
        float4 raw = hp4[(size_t)n * 8 + chunk];
        const __half2* hh = (const __half2*)&raw;
#pragma unroll
        for (int k = 0; k < 4; ++k) acc[k] = __hadd2(acc[k], hh[k]);
    }
    for (int jj = 0; jj < cnt; jj += 64) {
        int c = (jj + lane < cnt) ? sorted_col[start + jj + lane] : N;  // N = zero row
        int m = cnt - jj; if (m > 64) m = 64;
        int octs = (m + 7) >> 3;
        for (int j = 0; j < octs; ++j) {
            int cj = __shfl(c, j * 8 + eslot, 64);
            float4 raw = hp4[(size_t)cj * 8 + chunk];
            const __half2* hh = (const __half2*)&raw;
#pragma unroll
            for (int k = 0; k < 4; ++k) acc[k] = __hadd2(acc[k], hh[k]);
        }
    }
    // to fp32, reduce across eslot (xor bits 3,4,5)
    float af[8];
#pragma unroll
    for (int k = 0; k < 4; ++k) {
        float2 f = __half22float2(acc[k]);
        af[2 * k] = f.x; af[2 * k + 1] = f.y;
    }
#pragma unroll
    for (int s = 8; s <= 32; s <<= 1)
#pragma unroll
        for (int k = 0; k < 8; ++k) af[k] += __shfl_xor(af[k], s, 64);
    float dn = dinv[n];
    float4 b1a = ((const float4*)b1)[chunk * 2];
    float4 b1b = ((const float4*)b1)[chunk * 2 + 1];
    float h1[8];
    h1[0] = fmaxf(fmaf(dn, af[0], b1a.x), 0.f);
    h1[1] = fmaxf(fmaf(dn, af[1], b1a.y), 0.f);
    h1[2] = fmaxf(fmaf(dn, af[2], b1a.z), 0.f);
    h1[3] = fmaxf(fmaf(dn, af[3], b1a.w), 0.f);
    h1[4] = fmaxf(fmaf(dn, af[4], b1b.x), 0.f);
    h1[5] = fmaxf(fmaf(dn, af[5], b1b.y), 0.f);
    h1[6] = fmaxf(fmaf(dn, af[6], b1b.z), 0.f);
    h1[7] = fmaxf(fmaf(dn, af[7], b1b.w), 0.f);
    float p0 = 0.f, p1 = 0.f;
#pragma unroll
    for (int k = 0; k < 4; ++k) {   // float4 = W2 rows {8c+2k, 8c+2k+1}
        float4 w = ((const float4*)W2)[chunk * 4 + k];
        p0 = fmaf(h1[2 * k], w.x, p0); p1 = fmaf(h1[2 * k], w.y, p1);
        p0 = fmaf(h1[2 * k + 1], w.z, p0); p1 = fmaf(h1[2 * k + 1], w.w, p1);
    }
#pragma unroll
    for (int s = 1; s <= 4; s <<= 1) {  // reduce across chunk (bits 0,1,2)
        p0 += __shfl_xor(p0, s, 64);
        p1 += __shfl_xor(p1, s, 64);
    }
    if (lane == 0) h2p[n] = make_float2(dn * p0, dn * p1);  // pre-scaled
}

// ---- 6. layer-2 agg + softmax: 16 lanes per node ---------------------------
__global__ __launch_bounds__(256) void k_agg2(const float2* __restrict__ h2p,
                                              const int* __restrict__ offsets,
                                              const int* __restrict__ sorted_col,
                                              const float* __restrict__ dinv,
                                              const float* __restrict__ b2,
                                              float2* __restrict__ out, int N) {
    int gtid = blockIdx.x * 256 + threadIdx.x;
    int n = gtid >> 4;
    int sub = threadIdx.x & 15;
    if (n >= N) return;
    int start = offsets[n], end = offsets[n + 1];
    float ax = 0.f, ay = 0.f;
    if (sub == 0) { float2 s = h2p[n]; ax = s.x; ay = s.y; }   // self (pre-scaled)
    for (int j = start + sub; j < end; j += 16) {
        float2 v = h2p[sorted_col[j]];
        ax += v.x; ay += v.y;
    }
#pragma unroll
    for (int s = 1; s <= 8; s <<= 1) {
        ax += __shfl_xor(ax, s, 64);
        ay += __shfl_xor(ay, s, 64);
    }
    if (sub == 0) {
        float dn = dinv[n];
        float l0 = fmaf(dn, ax, b2[0]), l1 = fmaf(dn, ay, b2[1]);
        float m = fmaxf(l0, l1);
        float e0 = __expf(l0 - m), e1 = __expf(l1 - m);
        float inv = 1.0f / (e0 + e1);
        out[n] = make_float2(e0 * inv, e1 * inv);
    }
}

extern "C" void kernel_launch(void* const* d_in, const int* in_sizes, int n_in,
                              void* d_out, int out_size, void* d_ws, size_t ws_size,
                              hipStream_t stream) {
    const float* x  = (const float*)d_in[0];
    const int*   ei = (const int*)d_in[1];
    const float* W1 = (const float*)d_in[2];
    const float* b1 = (const float*)d_in[3];
    const float* W2 = (const float*)d_in[4];
    const float* b2 = (const float*)d_in[5];
    float2* out = (float2*)d_out;

    const int N = in_sizes[0] / 64;     // 100000
    const int E = in_sizes[1] / 2;      // 1600000
    const int nb = NBKT(N);             // 391
    const int* row = ei;
    const int* col = ei + E;

    char* p = (char*)d_ws;
    auto alloc = [&](size_t bytes) -> void* {
        void* r = (void*)p;
        p += (bytes + 255) & ~(size_t)255;
        return r;
    };
    // bcnt and relcur MUST be one contiguous block: a single memset clears
    // both (R4 bug: separate aligned allocs left relcur partially 0xAA).
    int*   bcnt    = (int*)alloc(784 * 4);          // [0..391]=bcnt, [392..783]=relcur
    int*   relcur  = bcnt + 392;
    int*   offsets = (int*)alloc((size_t)(N + 1) * 4);
    float* dinv    = (float*)alloc((size_t)N * 4);
    unsigned long long* pairbuf = (unsigned long long*)alloc((size_t)E * 8);
    int*   scol    = (int*)alloc((size_t)E * 4);
    __half* hp     = (__half*)alloc((size_t)(N + 1) * 64 * 2);  // +1 zero row
    float2* h2p    = (float2*)alloc((size_t)N * 8);

    const int nTile = (E + 4095) / 4096;  // 391

    hipMemsetAsync(bcnt, 0, 784 * 4, stream);   // bcnt + relcur, exact block
    k_bucketcount<<<nTile, 256, 0, stream>>>(row, bcnt, hp, E, nb, N);
    k_bin<<<nTile, 256, 0, stream>>>(row, col, bcnt, relcur, pairbuf, E, nb);
    k_sortnode<<<nb, 256, 0, stream>>>(pairbuf, bcnt, scol, offsets, dinv, N, E);
    k_gemm1<<<512, 256, 0, stream>>>(x, W1, dinv, hp, N);
    k_agg1<<<(N + 3) / 4, 256, 0, stream>>>(hp, offsets, scol, dinv, b1, W2, h2p, N);
    k_agg2<<<(N * 16 + 255) / 256, 256, 0, stream>>>(h2p, offsets, scol, dinv, b2, out, N);
}

// Round 6
// 202.614 us; speedup vs baseline: 2.3048x; 1.1300x over previous
//
#include <hip/hip_runtime.h>
#include <hip/hip_fp16.h>

// GCN 2-layer forward: out = softmax( A_norm @ relu(A_norm @ (x@W1) + b1) @ W2 + b2 )
// A_norm = D^-1/2 (A + I) D^-1/2, edges are col->row (row = target).
//
// R5 -> R6: agg1 was epilogue-bound (2 gather instr vs ~150 VALU instr per
// node; VALU 40%, HBM 19%, nothing saturated). New agg1: 8 nodes per wave
// (slot=lane>>3 owns a node, chunk=lane&7 owns 8 features). Gathers are
// independent across iterations and 4-deep unrolled (4 col-loads + 4 row
// gathers in flight); epilogue has NO cross-slot reduction (features stay in
// slot) -> ~6 instr/node. Exhausted slots read scol[E]=N sentinel -> zero-row
// gather (L1-hot), branch-free.

#define NBKT(n) (((n) + 255) >> 8)

// ---- 1. per-bucket histogram of row>>8 (+ zero hp row N) -------------------
__global__ __launch_bounds__(256) void k_bucketcount(const int* __restrict__ row,
                                                     int* __restrict__ bcnt,
                                                     __half* __restrict__ hp,
                                                     int E, int nb, int N) {
    __shared__ int cnt[392];
    int tid = threadIdx.x;
    int base = blockIdx.x * 4096;
    int m = E - base; if (m > 4096) m = 4096;
    for (int t = tid; t < nb; t += 256) cnt[t] = 0;
    __syncthreads();
    for (int i = tid; i < m; i += 256) atomicAdd(&cnt[row[base + i] >> 8], 1);
    __syncthreads();
    for (int t = tid; t < nb; t += 256) {
        int v = cnt[t];
        if (v > 0) atomicAdd(&bcnt[t], v);
    }
    if (blockIdx.x == 0 && tid < 32) ((int*)(hp + (size_t)N * 64))[tid] = 0;
}

// ---- 2. bin edges into 256-node buckets (coalesced pair runs) --------------
__global__ __launch_bounds__(256) void k_bin(const int* __restrict__ row,
                                             const int* __restrict__ col,
                                             const int* __restrict__ bcnt,
                                             int* __restrict__ relcur,
                                             unsigned long long* __restrict__ pairbuf,
                                             int E, int nb) {
    __shared__ unsigned long long items[4096];
    __shared__ int cnt[392];     // tile-local bucket counts
    __shared__ int start0[392];  // tile-local bucket starts
    __shared__ int cursor[392];
    __shared__ int gb[392];      // global bucket bases (scan of bcnt)
    __shared__ int gbase[392];

    int tid = threadIdx.x;
    int base = blockIdx.x * 4096;
    int m = E - base; if (m > 4096) m = 4096;

    for (int t = tid; t < nb; t += 256) cnt[t] = 0;
    __syncthreads();
    for (int i = tid; i < m; i += 256) atomicAdd(&cnt[row[base + i] >> 8], 1);
    __syncthreads();
    // two parallel wave-scans: wave0 scans tile counts, wave1 scans global bcnt
    if (tid < 64) {
        int lane = tid, running = 0;
        for (int ch = 0; ch < 7; ++ch) {
            int idx = ch * 64 + lane;
            int v = (idx < nb) ? cnt[idx] : 0;
            int s = v;
#pragma unroll
            for (int off = 1; off < 64; off <<= 1) {
                int t = __shfl_up(s, off, 64);
                if (lane >= off) s += t;
            }
            if (idx < nb) { start0[idx] = running + s - v; cursor[idx] = running + s - v; }
            running += __shfl(s, 63, 64);
        }
    } else if (tid < 128) {
        int lane = tid - 64, running = 0;
        for (int ch = 0; ch < 7; ++ch) {
            int idx = ch * 64 + lane;
            int v = (idx < nb) ? bcnt[idx] : 0;
            int s = v;
#pragma unroll
            for (int off = 1; off < 64; off <<= 1) {
                int t = __shfl_up(s, off, 64);
                if (lane >= off) s += t;
            }
            if (idx < nb) gb[idx] = running + s - v;
            running += __shfl(s, 63, 64);
        }
    }
    __syncthreads();
    for (int i = tid; i < m; i += 256) {
        int r = row[base + i];
        int c = col[base + i];
        int pos = atomicAdd(&cursor[r >> 8], 1);
        items[pos] = ((unsigned long long)(unsigned)r << 32) | (unsigned)c;
    }
    __syncthreads();
    for (int t = tid; t < nb; t += 256) {
        int cv = cnt[t];
        if (cv > 0) gbase[t] = gb[t] + atomicAdd(&relcur[t], cv);
    }
    __syncthreads();
    for (int i = tid; i < m; i += 256) {
        unsigned long long it = items[i];
        int b = ((int)(it >> 32)) >> 8;
        pairbuf[gbase[b] + (i - start0[b])] = it;
    }
}

// ---- 3. per-bucket counting sort -> scol, offsets, dinv --------------------
__global__ __launch_bounds__(256) void k_sortnode(const unsigned long long* __restrict__ pairbuf,
                                                  const int* __restrict__ bcnt,
                                                  int* __restrict__ scol,
                                                  int* __restrict__ offsets,
                                                  float* __restrict__ dinv,
                                                  int N, int E) {
    __shared__ int ps[256];
    __shared__ int cnt[256];
    __shared__ int tmp[256];
    __shared__ int cur[256];
    int b = blockIdx.x;
    int tid = threadIdx.x;
    // lo = sum(bcnt[0..b))
    int v = (tid < b) ? bcnt[tid] : 0;
    if (tid + 256 < b) v += bcnt[tid + 256];
    ps[tid] = v;
    __syncthreads();
    for (int s = 128; s >= 1; s >>= 1) {
        if (tid < s) ps[tid] += ps[tid + s];
        __syncthreads();
    }
    int lo = ps[0];
    int hi = lo + bcnt[b];
    cnt[tid] = 0;
    __syncthreads();
    for (int i = lo + tid; i < hi; i += 256)
        atomicAdd(&cnt[(int)(pairbuf[i] >> 32) & 255], 1);
    __syncthreads();
    // exclusive scan of cnt
    int cv = cnt[tid];
    tmp[tid] = cv;
    __syncthreads();
    for (int d = 1; d < 256; d <<= 1) {
        int t = (tid >= (unsigned)d) ? tmp[tid - d] : 0;
        __syncthreads();
        if (tid >= (unsigned)d) tmp[tid] += t;
        __syncthreads();
    }
    int excl = tmp[tid] - cv;
    int n = (b << 8) + tid;
    if (n < N) {
        offsets[n] = lo + excl;
        dinv[n] = rsqrtf((float)(cv + 1));  // +1 self-loop
    }
    cur[tid] = lo + excl;
    if (b == 0 && tid == 0) { offsets[N] = E; scol[E] = N; }  // sentinel -> zero row
    __syncthreads();
    for (int i = lo + tid; i < hi; i += 256) {
        unsigned long long it = pairbuf[i];
        int r = (int)(it >> 32);
        int pos = atomicAdd(&cur[r & 255], 1);
        scol[pos] = (int)(it & 0xffffffffu);
    }
}

// ---- 4. hp[n][f] = fp16( dinv[n] * (x @ W1)[n][f] ) ------------------------
__global__ __launch_bounds__(256) void k_gemm1(const float* __restrict__ x,
                                               const float* __restrict__ W1,
                                               const float* __restrict__ dinv,
                                               __half* __restrict__ hp, int N) {
    int lane = threadIdx.x & 63;
    float w1c[64];
#pragma unroll
    for (int k = 0; k < 64; ++k) w1c[k] = W1[k * 64 + lane];
    int wv = (int)((blockIdx.x * 256 + threadIdx.x) >> 6);
    int nw = (int)((gridDim.x * 256) >> 6);
    for (int n = wv; n < N; n += nw) {
        int nu = __builtin_amdgcn_readfirstlane(n);
        const float* xr = x + (size_t)nu * 64;
        float a0 = 0.f, a1 = 0.f, a2 = 0.f, a3 = 0.f;
#pragma unroll
        for (int k = 0; k < 64; k += 4) {
            a0 = fmaf(xr[k + 0], w1c[k + 0], a0);
            a1 = fmaf(xr[k + 1], w1c[k + 1], a1);
            a2 = fmaf(xr[k + 2], w1c[k + 2], a2);
            a3 = fmaf(xr[k + 3], w1c[k + 3], a3);
        }
        float acc = (a0 + a1) + (a2 + a3);
        hp[(size_t)nu * 64 + lane] = __float2half(dinv[nu] * acc);
    }
}

// ---- 5. layer-1 agg + relu(+b1) + 64->2 projection, fused ------------------
// Wave = 8 nodes. slot = lane>>3 owns node wid*8+slot; chunk = lane&7 owns
// features 8chunk..8chunk+7 (16B of the 128B row). Each gather instruction
// covers 8 edges (one per slot); 4-deep unroll keeps 4 col-loads + 4 gathers
// in flight. No cross-slot feature reduction needed.
__global__ __launch_bounds__(256) void k_agg1(const __half* __restrict__ hp,
                                              const int* __restrict__ offsets,
                                              const int* __restrict__ sorted_col,
                                              const float* __restrict__ dinv,
                                              const float* __restrict__ b1,
                                              const float* __restrict__ W2,
                                              float2* __restrict__ h2p, int N, int E) {
    int lane = threadIdx.x & 63;
    int slot = lane >> 3;
    int chunk = lane & 7;
    int wid = (int)((blockIdx.x * 256 + threadIdx.x) >> 6);
    int n = wid * 8 + slot;
    int nc = (n < N) ? n : N;                 // clamped: row N is the zero row
    int start = offsets[nc];
    int end = offsets[(n < N) ? (n + 1) : N]; // n>=N -> start==end==E -> deg 0
    int deg = end - start;
    // max degree across the 8 slots (xor bits 3,4,5 of lane)
    int maxd = deg;
#pragma unroll
    for (int s = 8; s <= 32; s <<= 1) {
        int o = __shfl_xor(maxd, s, 64);
        maxd = (o > maxd) ? o : maxd;
    }
    const float4* hp4 = (const float4*)hp;    // row stride = 8 float4
    // self term (zero row for n>=N)
    float4 sr = hp4[(size_t)nc * 8 + chunk];
    __half2 acc0 = ((const __half2*)&sr)[0];
    __half2 acc1 = ((const __half2*)&sr)[1];
    __half2 acc2 = ((const __half2*)&sr)[2];
    __half2 acc3 = ((const __half2*)&sr)[3];
    for (int j0 = 0; j0 < maxd; j0 += 4) {
        // branch-free: exhausted slots read scol[E] = N (zero row)
        int a0 = (j0 + 0 < deg) ? (start + j0 + 0) : E;
        int a1 = (j0 + 1 < deg) ? (start + j0 + 1) : E;
        int a2 = (j0 + 2 < deg) ? (start + j0 + 2) : E;
        int a3 = (j0 + 3 < deg) ? (start + j0 + 3) : E;
        int c0 = sorted_col[a0];
        int c1 = sorted_col[a1];
        int c2 = sorted_col[a2];
        int c3 = sorted_col[a3];
        float4 r0 = hp4[(size_t)c0 * 8 + chunk];
        float4 r1 = hp4[(size_t)c1 * 8 + chunk];
        float4 r2 = hp4[(size_t)c2 * 8 + chunk];
        float4 r3 = hp4[(size_t)c3 * 8 + chunk];
        const __half2* h0 = (const __half2*)&r0;
        const __half2* h1_ = (const __half2*)&r1;
        const __half2* h2_ = (const __half2*)&r2;
        const __half2* h3 = (const __half2*)&r3;
        acc0 = __hadd2(acc0, h0[0]); acc1 = __hadd2(acc1, h0[1]);
        acc2 = __hadd2(acc2, h0[2]); acc3 = __hadd2(acc3, h0[3]);
        acc0 = __hadd2(acc0, h1_[0]); acc1 = __hadd2(acc1, h1_[1]);
        acc2 = __hadd2(acc2, h1_[2]); acc3 = __hadd2(acc3, h1_[3]);
        acc0 = __hadd2(acc0, h2_[0]); acc1 = __hadd2(acc1, h2_[1]);
        acc2 = __hadd2(acc2, h2_[2]); acc3 = __hadd2(acc3, h2_[3]);
        acc0 = __hadd2(acc0, h3[0]); acc1 = __hadd2(acc1, h3[1]);
        acc2 = __hadd2(acc2, h3[2]); acc3 = __hadd2(acc3, h3[3]);
    }
    // epilogue: all 64 features of node n live in its slot's 8 chunk-lanes
    float af[8];
    { float2 f;
      f = __half22float2(acc0); af[0] = f.x; af[1] = f.y;
      f = __half22float2(acc1); af[2] = f.x; af[3] = f.y;
      f = __half22float2(acc2); af[4] = f.x; af[5] = f.y;
      f = __half22float2(acc3); af[6] = f.x; af[7] = f.y; }
    float dn = dinv[(n < N) ? n : (N - 1)];
    float4 b1a = ((const float4*)b1)[chunk * 2];
    float4 b1b = ((const float4*)b1)[chunk * 2 + 1];
    float h1[8];
    h1[0] = fmaxf(fmaf(dn, af[0], b1a.x), 0.f);
    h1[1] = fmaxf(fmaf(dn, af[1], b1a.y), 0.f);
    h1[2] = fmaxf(fmaf(dn, af[2], b1a.z), 0.f);
    h1[3] = fmaxf(fmaf(dn, af[3], b1a.w), 0.f);
    h1[4] = fmaxf(fmaf(dn, af[4], b1b.x), 0.f);
    h1[5] = fmaxf(fmaf(dn, af[5], b1b.y), 0.f);
    h1[6] = fmaxf(fmaf(dn, af[6], b1b.z), 0.f);
    h1[7] = fmaxf(fmaf(dn, af[7], b1b.w), 0.f);
    float p0 = 0.f, p1 = 0.f;
#pragma unroll
    for (int k = 0; k < 4; ++k) {   // float4 = W2 rows {8c+2k, 8c+2k+1}
        float4 w = ((const float4*)W2)[chunk * 4 + k];
        p0 = fmaf(h1[2 * k], w.x, p0); p1 = fmaf(h1[2 * k], w.y, p1);
        p0 = fmaf(h1[2 * k + 1], w.z, p0); p1 = fmaf(h1[2 * k + 1], w.w, p1);
    }
#pragma unroll
    for (int s = 1; s <= 4; s <<= 1) {  // reduce across chunk (bits 0,1,2)
        p0 += __shfl_xor(p0, s, 64);
        p1 += __shfl_xor(p1, s, 64);
    }
    if (chunk == 0 && n < N) h2p[n] = make_float2(dn * p0, dn * p1);  // pre-scaled
}

// ---- 6. layer-2 agg + softmax: 16 lanes per node ---------------------------
__global__ __launch_bounds__(256) void k_agg2(const float2* __restrict__ h2p,
                                              const int* __restrict__ offsets,
                                              const int* __restrict__ sorted_col,
                                              const float* __restrict__ dinv,
                                              const float* __restrict__ b2,
                                              float2* __restrict__ out, int N) {
    int gtid = blockIdx.x * 256 + threadIdx.x;
    int n = gtid >> 4;
    int sub = threadIdx.x & 15;
    if (n >= N) return;
    int start = offsets[n], end = offsets[n + 1];
    float ax = 0.f, ay = 0.f;
    if (sub == 0) { float2 s = h2p[n]; ax = s.x; ay = s.y; }   // self (pre-scaled)
    for (int j = start + sub; j < end; j += 16) {
        float2 v = h2p[sorted_col[j]];
        ax += v.x; ay += v.y;
    }
#pragma unroll
    for (int s = 1; s <= 8; s <<= 1) {
        ax += __shfl_xor(ax, s, 64);
        ay += __shfl_xor(ay, s, 64);
    }
    if (sub == 0) {
        float dn = dinv[n];
        float l0 = fmaf(dn, ax, b2[0]), l1 = fmaf(dn, ay, b2[1]);
        float m = fmaxf(l0, l1);
        float e0 = __expf(l0 - m), e1 = __expf(l1 - m);
        float inv = 1.0f / (e0 + e1);
        out[n] = make_float2(e0 * inv, e1 * inv);
    }
}

extern "C" void kernel_launch(void* const* d_in, const int* in_sizes, int n_in,
                              void* d_out, int out_size, void* d_ws, size_t ws_size,
                              hipStream_t stream) {
    const float* x  = (const float*)d_in[0];
    const int*   ei = (const int*)d_in[1];
    const float* W1 = (const float*)d_in[2];
    const float* b1 = (const float*)d_in[3];
    const float* W2 = (const float*)d_in[4];
    const float* b2 = (const float*)d_in[5];
    float2* out = (float2*)d_out;

    const int N = in_sizes[0] / 64;     // 100000
    const int E = in_sizes[1] / 2;      // 1600000
    const int nb = NBKT(N);             // 391
    const int* row = ei;
    const int* col = ei + E;

    char* p = (char*)d_ws;
    auto alloc = [&](size_t bytes) -> void* {
        void* r = (void*)p;
        p += (bytes + 255) & ~(size_t)255;
        return r;
    };
    // bcnt and relcur: one contiguous block, single exact memset (R4 lesson).
    int*   bcnt    = (int*)alloc(784 * 4);          // [0..391]=bcnt, [392..783]=relcur
    int*   relcur  = bcnt + 392;
    int*   offsets = (int*)alloc((size_t)(N + 1) * 4);
    float* dinv    = (float*)alloc((size_t)N * 4);
    unsigned long long* pairbuf = (unsigned long long*)alloc((size_t)E * 8);
    int*   scol    = (int*)alloc((size_t)(E + 1) * 4);          // +1 sentinel
    __half* hp     = (__half*)alloc((size_t)(N + 1) * 64 * 2);  // +1 zero row
    float2* h2p    = (float2*)alloc((size_t)N * 8);

    const int nTile = (E + 4095) / 4096;  // 391

    hipMemsetAsync(bcnt, 0, 784 * 4, stream);   // bcnt + relcur, exact block
    k_bucketcount<<<nTile, 256, 0, stream>>>(row, bcnt, hp, E, nb, N);
    k_bin<<<nTile, 256, 0, stream>>>(row, col, bcnt, relcur, pairbuf, E, nb);
    k_sortnode<<<nb, 256, 0, stream>>>(pairbuf, bcnt, scol, offsets, dinv, N, E);
    k_gemm1<<<1024, 256, 0, stream>>>(x, W1, dinv, hp, N);
    const int nwaves = (N + 7) / 8;                  // 8 nodes per wave
    k_agg1<<<(nwaves + 3) / 4, 256, 0, stream>>>(hp, offsets, scol, dinv, b1, W2, h2p, N, E);
    k_agg2<<<(N * 16 + 255) / 256, 256, 0, stream>>>(h2p, offsets, scol, dinv, b2, out, N);
}

// Round 7
// 200.404 us; speedup vs baseline: 2.3302x; 1.0110x over previous
//
#include <hip/hip_runtime.h>
#include <hip/hip_fp16.h>

// GCN 2-layer forward: out = softmax( A_norm @ relu(A_norm @ (x@W1) + b1) @ W2 + b2 )
// A_norm = D^-1/2 (A + I) D^-1/2, edges are col->row (row = target).
//
// R6 -> R7: gemm1 was 48us with VGPR_Count=40 — the 64-float W1 column CANNOT
// be resident in 40 VGPRs; compiler rematerialized W1 loads per node (16KB L1
// restream/node ~= the whole 48us). Fix: __launch_bounds__(256,1) to allow
// VGPR headroom + grid 2048. Also: pairbuf entries packed to 32 bits
// ((r&255)<<24 | col, valid while N < 2^24) halving bin/sort traffic.

#define NBKT(n) (((n) + 255) >> 8)

// ---- 1. per-bucket histogram of row>>8 (+ zero hp row N) -------------------
__global__ __launch_bounds__(256) void k_bucketcount(const int* __restrict__ row,
                                                     int* __restrict__ bcnt,
                                                     __half* __restrict__ hp,
                                                     int E, int nb, int N) {
    __shared__ int cnt[392];
    int tid = threadIdx.x;
    int base = blockIdx.x * 4096;
    int m = E - base; if (m > 4096) m = 4096;
    for (int t = tid; t < nb; t += 256) cnt[t] = 0;
    __syncthreads();
    for (int i = tid; i < m; i += 256) atomicAdd(&cnt[row[base + i] >> 8], 1);
    __syncthreads();
    for (int t = tid; t < nb; t += 256) {
        int v = cnt[t];
        if (v > 0) atomicAdd(&bcnt[t], v);
    }
    if (blockIdx.x == 0 && tid < 32) ((int*)(hp + (size_t)N * 64))[tid] = 0;
}

// ---- 2. bin edges into 256-node buckets (coalesced packed runs) ------------
__global__ __launch_bounds__(256) void k_bin(const int* __restrict__ row,
                                             const int* __restrict__ col,
                                             const int* __restrict__ bcnt,
                                             int* __restrict__ relcur,
                                             unsigned* __restrict__ pairbuf,
                                             int E, int nb) {
    __shared__ unsigned items[4096];        // (r&255)<<24 | col
    __shared__ unsigned short bktid[4096];  // bucket of each staged item
    __shared__ int cnt[392];     // tile-local bucket counts
    __shared__ int start0[392];  // tile-local bucket starts
    __shared__ int cursor[392];
    __shared__ int gb[392];      // global bucket bases (scan of bcnt)
    __shared__ int gbase[392];

    int tid = threadIdx.x;
    int base = blockIdx.x * 4096;
    int m = E - base; if (m > 4096) m = 4096;

    for (int t = tid; t < nb; t += 256) cnt[t] = 0;
    __syncthreads();
    for (int i = tid; i < m; i += 256) atomicAdd(&cnt[row[base + i] >> 8], 1);
    __syncthreads();
    // two parallel wave-scans: wave0 scans tile counts, wave1 scans global bcnt
    if (tid < 64) {
        int lane = tid, running = 0;
        for (int ch = 0; ch < 7; ++ch) {
            int idx = ch * 64 + lane;
            int v = (idx < nb) ? cnt[idx] : 0;
            int s = v;
#pragma unroll
            for (int off = 1; off < 64; off <<= 1) {
                int t = __shfl_up(s, off, 64);
                if (lane >= off) s += t;
            }
            if (idx < nb) { start0[idx] = running + s - v; cursor[idx] = running + s - v; }
            running += __shfl(s, 63, 64);
        }
    } else if (tid < 128) {
        int lane = tid - 64, running = 0;
        for (int ch = 0; ch < 7; ++ch) {
            int idx = ch * 64 + lane;
            int v = (idx < nb) ? bcnt[idx] : 0;
            int s = v;
#pragma unroll
            for (int off = 1; off < 64; off <<= 1) {
                int t = __shfl_up(s, off, 64);
                if (lane >= off) s += t;
            }
            if (idx < nb) gb[idx] = running + s - v;
            running += __shfl(s, 63, 64);
        }
    }
    __syncthreads();
    for (int i = tid; i < m; i += 256) {
        int r = row[base + i];
        int c = col[base + i];
        int b = r >> 8;
        int pos = atomicAdd(&cursor[b], 1);
        items[pos] = ((unsigned)(r & 255) << 24) | (unsigned)c;
        bktid[pos] = (unsigned short)b;
    }
    __syncthreads();
    for (int t = tid; t < nb; t += 256) {
        int cv = cnt[t];
        if (cv > 0) gbase[t] = gb[t] + atomicAdd(&relcur[t], cv);
    }
    __syncthreads();
    for (int i = tid; i < m; i += 256) {
        int b = bktid[i];
        pairbuf[gbase[b] + (i - start0[b])] = items[i];
    }
}

// ---- 3. per-bucket counting sort -> scol, offsets, dinv --------------------
__global__ __launch_bounds__(256) void k_sortnode(const unsigned* __restrict__ pairbuf,
                                                  const int* __restrict__ bcnt,
                                                  int* __restrict__ scol,
                                                  int* __restrict__ offsets,
                                                  float* __restrict__ dinv,
                                                  int N, int E) {
    __shared__ int ps[256];
    __shared__ int cnt[256];
    __shared__ int tmp[256];
    __shared__ int cur[256];
    int b = blockIdx.x;
    int tid = threadIdx.x;
    // lo = sum(bcnt[0..b))
    int v = (tid < b) ? bcnt[tid] : 0;
    if (tid + 256 < b) v += bcnt[tid + 256];
    ps[tid] = v;
    __syncthreads();
    for (int s = 128; s >= 1; s >>= 1) {
        if (tid < s) ps[tid] += ps[tid + s];
        __syncthreads();
    }
    int lo = ps[0];
    int hi = lo + bcnt[b];
    cnt[tid] = 0;
    __syncthreads();
    for (int i = lo + tid; i < hi; i += 256)
        atomicAdd(&cnt[pairbuf[i] >> 24], 1);
    __syncthreads();
    // exclusive scan of cnt
    int cv = cnt[tid];
    tmp[tid] = cv;
    __syncthreads();
    for (int d = 1; d < 256; d <<= 1) {
        int t = (tid >= (unsigned)d) ? tmp[tid - d] : 0;
        __syncthreads();
        if (tid >= (unsigned)d) tmp[tid] += t;
        __syncthreads();
    }
    int excl = tmp[tid] - cv;
    int n = (b << 8) + tid;
    if (n < N) {
        offsets[n] = lo + excl;
        dinv[n] = rsqrtf((float)(cv + 1));  // +1 self-loop
    }
    cur[tid] = lo + excl;
    if (b == 0 && tid == 0) { offsets[N] = E; scol[E] = N; }  // sentinel -> zero row
    __syncthreads();
    for (int i = lo + tid; i < hi; i += 256) {
        unsigned it = pairbuf[i];
        int pos = atomicAdd(&cur[it >> 24], 1);
        scol[pos] = (int)(it & 0xFFFFFFu);
    }
}

// ---- 4. hp[n][f] = fp16( dinv[n] * (x @ W1)[n][f] ) ------------------------
// __launch_bounds__(256,1): allow >64 VGPRs so the W1 column STAYS RESIDENT
// (R6: plain bounds gave VGPR=40 -> compiler rematerialized W1 loads per node,
// restreaming 16KB/node through L1 = the whole 48us).
__global__ __launch_bounds__(256, 1) void k_gemm1(const float* __restrict__ x,
                                                  const float* __restrict__ W1,
                                                  const float* __restrict__ dinv,
                                                  __half* __restrict__ hp, int N) {
    int lane = threadIdx.x & 63;
    float w1c[64];
#pragma unroll
    for (int k = 0; k < 64; ++k) w1c[k] = W1[k * 64 + lane];
    int wv = (int)((blockIdx.x * 256 + threadIdx.x) >> 6);
    int nw = (int)((gridDim.x * 256) >> 6);
    for (int n = wv; n < N; n += nw) {
        int nu = __builtin_amdgcn_readfirstlane(n);
        const float* xr = x + (size_t)nu * 64;
        float a0 = 0.f, a1 = 0.f, a2 = 0.f, a3 = 0.f;
#pragma unroll
        for (int k = 0; k < 64; k += 4) {
            a0 = fmaf(xr[k + 0], w1c[k + 0], a0);
            a1 = fmaf(xr[k + 1], w1c[k + 1], a1);
            a2 = fmaf(xr[k + 2], w1c[k + 2], a2);
            a3 = fmaf(xr[k + 3], w1c[k + 3], a3);
        }
        float acc = (a0 + a1) + (a2 + a3);
        hp[(size_t)nu * 64 + lane] = __float2half(dinv[nu] * acc);
    }
}

// ---- 5. layer-1 agg + relu(+b1) + 64->2 projection, fused ------------------
// Wave = 8 nodes. slot = lane>>3 owns node wid*8+slot; chunk = lane&7 owns
// features 8chunk..8chunk+7 (16B of the 128B row). Each gather instruction
// covers 8 edges (one per slot); 4-deep unroll keeps 4 col-loads + 4 gathers
// in flight. No cross-slot feature reduction needed.
__global__ __launch_bounds__(256) void k_agg1(const __half* __restrict__ hp,
                                              const int* __restrict__ offsets,
                                              const int* __restrict__ sorted_col,
                                              const float* __restrict__ dinv,
                                              const float* __restrict__ b1,
                                              const float* __restrict__ W2,
                                              float2* __restrict__ h2p, int N, int E) {
    int lane = threadIdx.x & 63;
    int slot = lane >> 3;
    int chunk = lane & 7;
    int wid = (int)((blockIdx.x * 256 + threadIdx.x) >> 6);
    int n = wid * 8 + slot;
    int nc = (n < N) ? n : N;                 // clamped: row N is the zero row
    int start = offsets[nc];
    int end = offsets[(n < N) ? (n + 1) : N]; // n>=N -> start==end==E -> deg 0
    int deg = end - start;
    // max degree across the 8 slots (xor bits 3,4,5 of lane)
    int maxd = deg;
#pragma unroll
    for (int s = 8; s <= 32; s <<= 1) {
        int o = __shfl_xor(maxd, s, 64);
        maxd = (o > maxd) ? o : maxd;
    }
    const float4* hp4 = (const float4*)hp;    // row stride = 8 float4
    // self term (zero row for n>=N)
    float4 sr = hp4[(size_t)nc * 8 + chunk];
    __half2 acc0 = ((const __half2*)&sr)[0];
    __half2 acc1 = ((const __half2*)&sr)[1];
    __half2 acc2 = ((const __half2*)&sr)[2];
    __half2 acc3 = ((const __half2*)&sr)[3];
    for (int j0 = 0; j0 < maxd; j0 += 4) {
        // branch-free: exhausted slots read scol[E] = N (zero row)
        int a0 = (j0 + 0 < deg) ? (start + j0 + 0) : E;
        int a1 = (j0 + 1 < deg) ? (start + j0 + 1) : E;
        int a2 = (j0 + 2 < deg) ? (start + j0 + 2) : E;
        int a3 = (j0 + 3 < deg) ? (start + j0 + 3) : E;
        int c0 = sorted_col[a0];
        int c1 = sorted_col[a1];
        int c2 = sorted_col[a2];
        int c3 = sorted_col[a3];
        float4 r0 = hp4[(size_t)c0 * 8 + chunk];
        float4 r1 = hp4[(size_t)c1 * 8 + chunk];
        float4 r2 = hp4[(size_t)c2 * 8 + chunk];
        float4 r3 = hp4[(size_t)c3 * 8 + chunk];
        const __half2* h0 = (const __half2*)&r0;
        const __half2* h1_ = (const __half2*)&r1;
        const __half2* h2_ = (const __half2*)&r2;
        const __half2* h3 = (const __half2*)&r3;
        acc0 = __hadd2(acc0, h0[0]); acc1 = __hadd2(acc1, h0[1]);
        acc2 = __hadd2(acc2, h0[2]); acc3 = __hadd2(acc3, h0[3]);
        acc0 = __hadd2(acc0, h1_[0]); acc1 = __hadd2(acc1, h1_[1]);
        acc2 = __hadd2(acc2, h1_[2]); acc3 = __hadd2(acc3, h1_[3]);
        acc0 = __hadd2(acc0, h2_[0]); acc1 = __hadd2(acc1, h2_[1]);
        acc2 = __hadd2(acc2, h2_[2]); acc3 = __hadd2(acc3, h2_[3]);
        acc0 = __hadd2(acc0, h3[0]); acc1 = __hadd2(acc1, h3[1]);
        acc2 = __hadd2(acc2, h3[2]); acc3 = __hadd2(acc3, h3[3]);
    }
    // epilogue: all 64 features of node n live in its slot's 8 chunk-lanes
    float af[8];
    { float2 f;
      f = __half22float2(acc0); af[0] = f.x; af[1] = f.y;
      f = __half22float2(acc1); af[2] = f.x; af[3] = f.y;
      f = __half22float2(acc2); af[4] = f.x; af[5] = f.y;
      f = __half22float2(acc3); af[6] = f.x; af[7] = f.y; }
    float dn = dinv[(n < N) ? n : (N - 1)];
    float4 b1a = ((const float4*)b1)[chunk * 2];
    float4 b1b = ((const float4*)b1)[chunk * 2 + 1];
    float h1[8];
    h1[0] = fmaxf(fmaf(dn, af[0], b1a.x), 0.f);
    h1[1] = fmaxf(fmaf(dn, af[1], b1a.y), 0.f);
    h1[2] = fmaxf(fmaf(dn, af[2], b1a.z), 0.f);
    h1[3] = fmaxf(fmaf(dn, af[3], b1a.w), 0.f);
    h1[4] = fmaxf(fmaf(dn, af[4], b1b.x), 0.f);
    h1[5] = fmaxf(fmaf(dn, af[5], b1b.y), 0.f);
    h1[6] = fmaxf(fmaf(dn, af[6], b1b.z), 0.f);
    h1[7] = fmaxf(fmaf(dn, af[7], b1b.w), 0.f);
    float p0 = 0.f, p1 = 0.f;
#pragma unroll
    for (int k = 0; k < 4; ++k) {   // float4 = W2 rows {8c+2k, 8c+2k+1}
        float4 w = ((const float4*)W2)[chunk * 4 + k];
        p0 = fmaf(h1[2 * k], w.x, p0); p1 = fmaf(h1[2 * k], w.y, p1);
        p0 = fmaf(h1[2 * k + 1], w.z, p0); p1 = fmaf(h1[2 * k + 1], w.w, p1);
    }
#pragma unroll
    for (int s = 1; s <= 4; s <<= 1) {  // reduce across chunk (bits 0,1,2)
        p0 += __shfl_xor(p0, s, 64);
        p1 += __shfl_xor(p1, s, 64);
    }
    if (chunk == 0 && n < N) h2p[n] = make_float2(dn * p0, dn * p1);  // pre-scaled
}

// ---- 6. layer-2 agg + softmax: 16 lanes per node ---------------------------
__global__ __launch_bounds__(256) void k_agg2(const float2* __restrict__ h2p,
                                              const int* __restrict__ offsets,
                                              const int* __restrict__ sorted_col,
                                              const float* __restrict__ dinv,
                                              const float* __restrict__ b2,
                                              float2* __restrict__ out, int N) {
    int gtid = blockIdx.x * 256 + threadIdx.x;
    int n = gtid >> 4;
    int sub = threadIdx.x & 15;
    if (n >= N) return;
    int start = offsets[n], end = offsets[n + 1];
    float ax = 0.f, ay = 0.f;
    if (sub == 0) { float2 s = h2p[n]; ax = s.x; ay = s.y; }   // self (pre-scaled)
    for (int j = start + sub; j < end; j += 16) {
        float2 v = h2p[sorted_col[j]];
        ax += v.x; ay += v.y;
    }
#pragma unroll
    for (int s = 1; s <= 8; s <<= 1) {
        ax += __shfl_xor(ax, s, 64);
        ay += __shfl_xor(ay, s, 64);
    }
    if (sub == 0) {
        float dn = dinv[n];
        float l0 = fmaf(dn, ax, b2[0]), l1 = fmaf(dn, ay, b2[1]);
        float m = fmaxf(l0, l1);
        float e0 = __expf(l0 - m), e1 = __expf(l1 - m);
        float inv = 1.0f / (e0 + e1);
        out[n] = make_float2(e0 * inv, e1 * inv);
    }
}

extern "C" void kernel_launch(void* const* d_in, const int* in_sizes, int n_in,
                              void* d_out, int out_size, void* d_ws, size_t ws_size,
                              hipStream_t stream) {
    const float* x  = (const float*)d_in[0];
    const int*   ei = (const int*)d_in[1];
    const float* W1 = (const float*)d_in[2];
    const float* b1 = (const float*)d_in[3];
    const float* W2 = (const float*)d_in[4];
    const float* b2 = (const float*)d_in[5];
    float2* out = (float2*)d_out;

    const int N = in_sizes[0] / 64;     // 100000  (packing assumes N < 2^24)
    const int E = in_sizes[1] / 2;      // 1600000
    const int nb = NBKT(N);             // 391
    const int* row = ei;
    const int* col = ei + E;

    char* p = (char*)d_ws;
    auto alloc = [&](size_t bytes) -> void* {
        void* r = (void*)p;
        p += (bytes + 255) & ~(size_t)255;
        return r;
    };
    // bcnt and relcur: one contiguous block, single exact memset (R4 lesson).
    int*   bcnt    = (int*)alloc(784 * 4);          // [0..391]=bcnt, [392..783]=relcur
    int*   relcur  = bcnt + 392;
    int*   offsets = (int*)alloc((size_t)(N + 1) * 4);
    float* dinv    = (float*)alloc((size_t)N * 4);
    unsigned* pairbuf = (unsigned*)alloc((size_t)E * 4);        // packed 32-bit
    int*   scol    = (int*)alloc((size_t)(E + 1) * 4);          // +1 sentinel
    __half* hp     = (__half*)alloc((size_t)(N + 1) * 64 * 2);  // +1 zero row
    float2* h2p    = (float2*)alloc((size_t)N * 8);

    const int nTile = (E + 4095) / 4096;  // 391

    hipMemsetAsync(bcnt, 0, 784 * 4, stream);   // bcnt + relcur, exact block
    k_bucketcount<<<nTile, 256, 0, stream>>>(row, bcnt, hp, E, nb, N);
    k_bin<<<nTile, 256, 0, stream>>>(row, col, bcnt, relcur, pairbuf, E, nb);
    k_sortnode<<<nb, 256, 0, stream>>>(pairbuf, bcnt, scol, offsets, dinv, N, E);
    k_gemm1<<<2048, 256, 0, stream>>>(x, W1, dinv, hp, N);
    const int nwaves = (N + 7) / 8;                  // 8 nodes per wave
    k_agg1<<<(nwaves + 3) / 4, 256, 0, stream>>>(hp, offsets, scol, dinv, b1, W2, h2p, N, E);
    k_agg2<<<(N * 16 + 255) / 256, 256, 0, stream>>>(h2p, offsets, scol, dinv, b2, out, N);
}

// Round 8
// 181.792 us; speedup vs baseline: 2.5688x; 1.1024x over previous
//
#include <hip/hip_runtime.h>
#include <hip/hip_fp16.h>

// GCN 2-layer forward: out = softmax( A_norm @ relu(A_norm @ (x@W1) + b1) @ W2 + b2 )
// A_norm = D^-1/2 (A + I) D^-1/2, edges are col->row (row = target).
//
// R7 -> R8: launch_bounds(256,1) did NOT fix gemm1 (VGPR stayed 40 — the
// compiler rematerializes the W1 column regardless; 6.4M vmem instrs = issue
// bound at 46us). Replace gemm1 with MFMA (mfma_f32_16x16x32_f16): one wave
// does a 16-node x 64-feature tile in 8 MFMAs + 4 float4 loads + 16 stores.
// Layouts (guide-verified): A[m=lane&15][k=q*8+j], B[k=q*8+j][n=lane&15],
// D col=lane&15 row=q*4+reg. N % 16 == 0 -> no tail.

#define NBKT(n) (((n) + 255) >> 8)

typedef _Float16 f16x8 __attribute__((ext_vector_type(8)));
typedef float f32x4 __attribute__((ext_vector_type(4)));

// ---- 1. per-bucket histogram of row>>8 (+ zero hp row N) -------------------
__global__ __launch_bounds__(256) void k_bucketcount(const int* __restrict__ row,
                                                     int* __restrict__ bcnt,
                                                     __half* __restrict__ hp,
                                                     int E, int nb, int N) {
    __shared__ int cnt[392];
    int tid = threadIdx.x;
    int base = blockIdx.x * 4096;
    int m = E - base; if (m > 4096) m = 4096;
    for (int t = tid; t < nb; t += 256) cnt[t] = 0;
    __syncthreads();
    for (int i = tid; i < m; i += 256) atomicAdd(&cnt[row[base + i] >> 8], 1);
    __syncthreads();
    for (int t = tid; t < nb; t += 256) {
        int v = cnt[t];
        if (v > 0) atomicAdd(&bcnt[t], v);
    }
    if (blockIdx.x == 0 && tid < 32) ((int*)(hp + (size_t)N * 64))[tid] = 0;
}

// ---- 2. bin edges into 256-node buckets (coalesced packed runs) ------------
__global__ __launch_bounds__(256) void k_bin(const int* __restrict__ row,
                                             const int* __restrict__ col,
                                             const int* __restrict__ bcnt,
                                             int* __restrict__ relcur,
                                             unsigned* __restrict__ pairbuf,
                                             int E, int nb) {
    __shared__ unsigned items[4096];        // (r&255)<<24 | col
    __shared__ unsigned short bktid[4096];  // bucket of each staged item
    __shared__ int cnt[392];     // tile-local bucket counts
    __shared__ int start0[392];  // tile-local bucket starts
    __shared__ int cursor[392];
    __shared__ int gb[392];      // global bucket bases (scan of bcnt)
    __shared__ int gbase[392];

    int tid = threadIdx.x;
    int base = blockIdx.x * 4096;
    int m = E - base; if (m > 4096) m = 4096;

    for (int t = tid; t < nb; t += 256) cnt[t] = 0;
    __syncthreads();
    for (int i = tid; i < m; i += 256) atomicAdd(&cnt[row[base + i] >> 8], 1);
    __syncthreads();
    // two parallel wave-scans: wave0 scans tile counts, wave1 scans global bcnt
    if (tid < 64) {
        int lane = tid, running = 0;
        for (int ch = 0; ch < 7; ++ch) {
            int idx = ch * 64 + lane;
            int v = (idx < nb) ? cnt[idx] : 0;
            int s = v;
#pragma unroll
            for (int off = 1; off < 64; off <<= 1) {
                int t = __shfl_up(s, off, 64);
                if (lane >= off) s += t;
            }
            if (idx < nb) { start0[idx] = running + s - v; cursor[idx] = running + s - v; }
            running += __shfl(s, 63, 64);
        }
    } else if (tid < 128) {
        int lane = tid - 64, running = 0;
        for (int ch = 0; ch < 7; ++ch) {
            int idx = ch * 64 + lane;
            int v = (idx < nb) ? bcnt[idx] : 0;
            int s = v;
#pragma unroll
            for (int off = 1; off < 64; off <<= 1) {
                int t = __shfl_up(s, off, 64);
                if (lane >= off) s += t;
            }
            if (idx < nb) gb[idx] = running + s - v;
            running += __shfl(s, 63, 64);
        }
    }
    __syncthreads();
    for (int i = tid; i < m; i += 256) {
        int r = row[base + i];
        int c = col[base + i];
        int b = r >> 8;
        int pos = atomicAdd(&cursor[b], 1);
        items[pos] = ((unsigned)(r & 255) << 24) | (unsigned)c;
        bktid[pos] = (unsigned short)b;
    }
    __syncthreads();
    for (int t = tid; t < nb; t += 256) {
        int cv = cnt[t];
        if (cv > 0) gbase[t] = gb[t] + atomicAdd(&relcur[t], cv);
    }
    __syncthreads();
    for (int i = tid; i < m; i += 256) {
        int b = bktid[i];
        pairbuf[gbase[b] + (i - start0[b])] = items[i];
    }
}

// ---- 3. per-bucket counting sort -> scol, offsets, dinv --------------------
__global__ __launch_bounds__(256) void k_sortnode(const unsigned* __restrict__ pairbuf,
                                                  const int* __restrict__ bcnt,
                                                  int* __restrict__ scol,
                                                  int* __restrict__ offsets,
                                                  float* __restrict__ dinv,
                                                  int N, int E) {
    __shared__ int ps[256];
    __shared__ int cnt[256];
    __shared__ int tmp[256];
    __shared__ int cur[256];
    int b = blockIdx.x;
    int tid = threadIdx.x;
    // lo = sum(bcnt[0..b))
    int v = (tid < b) ? bcnt[tid] : 0;
    if (tid + 256 < b) v += bcnt[tid + 256];
    ps[tid] = v;
    __syncthreads();
    for (int s = 128; s >= 1; s >>= 1) {
        if (tid < s) ps[tid] += ps[tid + s];
        __syncthreads();
    }
    int lo = ps[0];
    int hi = lo + bcnt[b];
    cnt[tid] = 0;
    __syncthreads();
    for (int i = lo + tid; i < hi; i += 256)
        atomicAdd(&cnt[pairbuf[i] >> 24], 1);
    __syncthreads();
    // exclusive scan of cnt
    int cv = cnt[tid];
    tmp[tid] = cv;
    __syncthreads();
    for (int d = 1; d < 256; d <<= 1) {
        int t = (tid >= (unsigned)d) ? tmp[tid - d] : 0;
        __syncthreads();
        if (tid >= (unsigned)d) tmp[tid] += t;
        __syncthreads();
    }
    int excl = tmp[tid] - cv;
    int n = (b << 8) + tid;
    if (n < N) {
        offsets[n] = lo + excl;
        dinv[n] = rsqrtf((float)(cv + 1));  // +1 self-loop
    }
    cur[tid] = lo + excl;
    if (b == 0 && tid == 0) { offsets[N] = E; scol[E] = N; }  // sentinel -> zero row
    __syncthreads();
    for (int i = lo + tid; i < hi; i += 256) {
        unsigned it = pairbuf[i];
        int pos = atomicAdd(&cur[it >> 24], 1);
        scol[pos] = (int)(it & 0xFFFFFFu);
    }
}

// ---- 4. hp = fp16(dinv * (x @ W1)) via MFMA --------------------------------
// Wave = 16-node x 64-feature tile. 8x mfma_f32_16x16x32_f16 per tile.
// B-frags (W1) preloaded once per wave (32 VGPRs).
__global__ __launch_bounds__(256, 2) void k_gemm1(const float* __restrict__ x,
                                                  const float* __restrict__ W1,
                                                  const float* __restrict__ dinv,
                                                  __half* __restrict__ hp, int N) {
    int lane = threadIdx.x & 63;
    int q = lane >> 4;          // quad 0..3
    int m = lane & 15;
    // B[k][n]: n = nt*16 + m, k = kk*32 + q*8 + j
    f16x8 bf[4][2];
#pragma unroll
    for (int nt = 0; nt < 4; ++nt)
#pragma unroll
        for (int kk = 0; kk < 2; ++kk)
#pragma unroll
            for (int j = 0; j < 8; ++j)
                bf[nt][kk][j] = (_Float16)W1[(kk * 32 + q * 8 + j) * 64 + nt * 16 + m];
    int wv = (int)((blockIdx.x * 256 + threadIdx.x) >> 6);
    int nw = (int)((gridDim.x * 256) >> 6);
    int T = N >> 4;             // N % 16 == 0
    for (int t = wv; t < T; t += nw) {
        // A[m][k]: row = t*16 + m, k = q*8+j (a0) / 32+q*8+j (a1)
        const float* xrow = x + (size_t)(t * 16 + m) * 64;
        float4 u0 = *(const float4*)(xrow + q * 8);
        float4 u1 = *(const float4*)(xrow + q * 8 + 4);
        float4 u2 = *(const float4*)(xrow + 32 + q * 8);
        float4 u3 = *(const float4*)(xrow + 32 + q * 8 + 4);
        f16x8 a0, a1;
        a0[0] = (_Float16)u0.x; a0[1] = (_Float16)u0.y; a0[2] = (_Float16)u0.z; a0[3] = (_Float16)u0.w;
        a0[4] = (_Float16)u1.x; a0[5] = (_Float16)u1.y; a0[6] = (_Float16)u1.z; a0[7] = (_Float16)u1.w;
        a1[0] = (_Float16)u2.x; a1[1] = (_Float16)u2.y; a1[2] = (_Float16)u2.z; a1[3] = (_Float16)u2.w;
        a1[4] = (_Float16)u3.x; a1[5] = (_Float16)u3.y; a1[6] = (_Float16)u3.z; a1[7] = (_Float16)u3.w;
        f32x4 ac0 = {0.f, 0.f, 0.f, 0.f}, ac1 = ac0, ac2 = ac0, ac3 = ac0;
        ac0 = __builtin_amdgcn_mfma_f32_16x16x32_f16(a0, bf[0][0], ac0, 0, 0, 0);
        ac1 = __builtin_amdgcn_mfma_f32_16x16x32_f16(a0, bf[1][0], ac1, 0, 0, 0);
        ac2 = __builtin_amdgcn_mfma_f32_16x16x32_f16(a0, bf[2][0], ac2, 0, 0, 0);
        ac3 = __builtin_amdgcn_mfma_f32_16x16x32_f16(a0, bf[3][0], ac3, 0, 0, 0);
        ac0 = __builtin_amdgcn_mfma_f32_16x16x32_f16(a1, bf[0][1], ac0, 0, 0, 0);
        ac1 = __builtin_amdgcn_mfma_f32_16x16x32_f16(a1, bf[1][1], ac1, 0, 0, 0);
        ac2 = __builtin_amdgcn_mfma_f32_16x16x32_f16(a1, bf[2][1], ac2, 0, 0, 0);
        ac3 = __builtin_amdgcn_mfma_f32_16x16x32_f16(a1, bf[3][1], ac3, 0, 0, 0);
        // D: col = m (within n-tile), row = q*4 + reg
#pragma unroll
        for (int reg = 0; reg < 4; ++reg) {
            int rr = t * 16 + q * 4 + reg;
            float dv = dinv[rr];
            __half* dst = hp + (size_t)rr * 64 + m;
            dst[0]  = __float2half(dv * ac0[reg]);
            dst[16] = __float2half(dv * ac1[reg]);
            dst[32] = __float2half(dv * ac2[reg]);
            dst[48] = __float2half(dv * ac3[reg]);
        }
    }
}

// ---- 5. layer-1 agg + relu(+b1) + 64->2 projection, fused ------------------
// Wave = 8 nodes. slot = lane>>3 owns node wid*8+slot; chunk = lane&7 owns
// features 8chunk..8chunk+7 (16B of the 128B row). 4-deep unrolled gathers.
__global__ __launch_bounds__(256) void k_agg1(const __half* __restrict__ hp,
                                              const int* __restrict__ offsets,
                                              const int* __restrict__ sorted_col,
                                              const float* __restrict__ dinv,
                                              const float* __restrict__ b1,
                                              const float* __restrict__ W2,
                                              float2* __restrict__ h2p, int N, int E) {
    int lane = threadIdx.x & 63;
    int slot = lane >> 3;
    int chunk = lane & 7;
    int wid = (int)((blockIdx.x * 256 + threadIdx.x) >> 6);
    int n = wid * 8 + slot;
    int nc = (n < N) ? n : N;                 // clamped: row N is the zero row
    int start = offsets[nc];
    int end = offsets[(n < N) ? (n + 1) : N]; // n>=N -> start==end==E -> deg 0
    int deg = end - start;
    // max degree across the 8 slots (xor bits 3,4,5 of lane)
    int maxd = deg;
#pragma unroll
    for (int s = 8; s <= 32; s <<= 1) {
        int o = __shfl_xor(maxd, s, 64);
        maxd = (o > maxd) ? o : maxd;
    }
    const float4* hp4 = (const float4*)hp;    // row stride = 8 float4
    // self term (zero row for n>=N)
    float4 sr = hp4[(size_t)nc * 8 + chunk];
    __half2 acc0 = ((const __half2*)&sr)[0];
    __half2 acc1 = ((const __half2*)&sr)[1];
    __half2 acc2 = ((const __half2*)&sr)[2];
    __half2 acc3 = ((const __half2*)&sr)[3];
    for (int j0 = 0; j0 < maxd; j0 += 4) {
        // branch-free: exhausted slots read scol[E] = N (zero row)
        int a0 = (j0 + 0 < deg) ? (start + j0 + 0) : E;
        int a1 = (j0 + 1 < deg) ? (start + j0 + 1) : E;
        int a2 = (j0 + 2 < deg) ? (start + j0 + 2) : E;
        int a3 = (j0 + 3 < deg) ? (start + j0 + 3) : E;
        int c0 = sorted_col[a0];
        int c1 = sorted_col[a1];
        int c2 = sorted_col[a2];
        int c3 = sorted_col[a3];
        float4 r0 = hp4[(size_t)c0 * 8 + chunk];
        float4 r1 = hp4[(size_t)c1 * 8 + chunk];
        float4 r2 = hp4[(size_t)c2 * 8 + chunk];
        float4 r3 = hp4[(size_t)c3 * 8 + chunk];
        const __half2* h0 = (const __half2*)&r0;
        const __half2* h1_ = (const __half2*)&r1;
        const __half2* h2_ = (const __half2*)&r2;
        const __half2* h3 = (const __half2*)&r3;
        acc0 = __hadd2(acc0, h0[0]); acc1 = __hadd2(acc1, h0[1]);
        acc2 = __hadd2(acc2, h0[2]); acc3 = __hadd2(acc3, h0[3]);
        acc0 = __hadd2(acc0, h1_[0]); acc1 = __hadd2(acc1, h1_[1]);
        acc2 = __hadd2(acc2, h1_[2]); acc3 = __hadd2(acc3, h1_[3]);
        acc0 = __hadd2(acc0, h2_[0]); acc1 = __hadd2(acc1, h2_[1]);
        acc2 = __hadd2(acc2, h2_[2]); acc3 = __hadd2(acc3, h2_[3]);
        acc0 = __hadd2(acc0, h3[0]); acc1 = __hadd2(acc1, h3[1]);
        acc2 = __hadd2(acc2, h3[2]); acc3 = __hadd2(acc3, h3[3]);
    }
    // epilogue: all 64 features of node n live in its slot's 8 chunk-lanes
    float af[8];
    { float2 f;
      f = __half22float2(acc0); af[0] = f.x; af[1] = f.y;
      f = __half22float2(acc1); af[2] = f.x; af[3] = f.y;
      f = __half22float2(acc2); af[4] = f.x; af[5] = f.y;
      f = __half22float2(acc3); af[6] = f.x; af[7] = f.y; }
    float dn = dinv[(n < N) ? n : (N - 1)];
    float4 b1a = ((const float4*)b1)[chunk * 2];
    float4 b1b = ((const float4*)b1)[chunk * 2 + 1];
    float h1[8];
    h1[0] = fmaxf(fmaf(dn, af[0], b1a.x), 0.f);
    h1[1] = fmaxf(fmaf(dn, af[1], b1a.y), 0.f);
    h1[2] = fmaxf(fmaf(dn, af[2], b1a.z), 0.f);
    h1[3] = fmaxf(fmaf(dn, af[3], b1a.w), 0.f);
    h1[4] = fmaxf(fmaf(dn, af[4], b1b.x), 0.f);
    h1[5] = fmaxf(fmaf(dn, af[5], b1b.y), 0.f);
    h1[6] = fmaxf(fmaf(dn, af[6], b1b.z), 0.f);
    h1[7] = fmaxf(fmaf(dn, af[7], b1b.w), 0.f);
    float p0 = 0.f, p1 = 0.f;
#pragma unroll
    for (int k = 0; k < 4; ++k) {   // float4 = W2 rows {8c+2k, 8c+2k+1}
        float4 w = ((const float4*)W2)[chunk * 4 + k];
        p0 = fmaf(h1[2 * k], w.x, p0); p1 = fmaf(h1[2 * k], w.y, p1);
        p0 = fmaf(h1[2 * k + 1], w.z, p0); p1 = fmaf(h1[2 * k + 1], w.w, p1);
    }
#pragma unroll
    for (int s = 1; s <= 4; s <<= 1) {  // reduce across chunk (bits 0,1,2)
        p0 += __shfl_xor(p0, s, 64);
        p1 += __shfl_xor(p1, s, 64);
    }
    if (chunk == 0 && n < N) h2p[n] = make_float2(dn * p0, dn * p1);  // pre-scaled
}

// ---- 6. layer-2 agg + softmax: 16 lanes per node ---------------------------
__global__ __launch_bounds__(256) void k_agg2(const float2* __restrict__ h2p,
                                              const int* __restrict__ offsets,
                                              const int* __restrict__ sorted_col,
                                              const float* __restrict__ dinv,
                                              const float* __restrict__ b2,
                                              float2* __restrict__ out, int N) {
    int gtid = blockIdx.x * 256 + threadIdx.x;
    int n = gtid >> 4;
    int sub = threadIdx.x & 15;
    if (n >= N) return;
    int start = offsets[n], end = offsets[n + 1];
    float ax = 0.f, ay = 0.f;
    if (sub == 0) { float2 s = h2p[n]; ax = s.x; ay = s.y; }   // self (pre-scaled)
    for (int j = start + sub; j < end; j += 16) {
        float2 v = h2p[sorted_col[j]];
        ax += v.x; ay += v.y;
    }
#pragma unroll
    for (int s = 1; s <= 8; s <<= 1) {
        ax += __shfl_xor(ax, s, 64);
        ay += __shfl_xor(ay, s, 64);
    }
    if (sub == 0) {
        float dn = dinv[n];
        float l0 = fmaf(dn, ax, b2[0]), l1 = fmaf(dn, ay, b2[1]);
        float m = fmaxf(l0, l1);
        float e0 = __expf(l0 - m), e1 = __expf(l1 - m);
        float inv = 1.0f / (e0 + e1);
        out[n] = make_float2(e0 * inv, e1 * inv);
    }
}

extern "C" void kernel_launch(void* const* d_in, const int* in_sizes, int n_in,
                              void* d_out, int out_size, void* d_ws, size_t ws_size,
                              hipStream_t stream) {
    const float* x  = (const float*)d_in[0];
    const int*   ei = (const int*)d_in[1];
    const float* W1 = (const float*)d_in[2];
    const float* b1 = (const float*)d_in[3];
    const float* W2 = (const float*)d_in[4];
    const float* b2 = (const float*)d_in[5];
    float2* out = (float2*)d_out;

    const int N = in_sizes[0] / 64;     // 100000  (packing assumes N < 2^24; N%16==0)
    const int E = in_sizes[1] / 2;      // 1600000
    const int nb = NBKT(N);             // 391
    const int* row = ei;
    const int* col = ei + E;

    char* p = (char*)d_ws;
    auto alloc = [&](size_t bytes) -> void* {
        void* r = (void*)p;
        p += (bytes + 255) & ~(size_t)255;
        return r;
    };
    // bcnt and relcur: one contiguous block, single exact memset (R4 lesson).
    int*   bcnt    = (int*)alloc(784 * 4);          // [0..391]=bcnt, [392..783]=relcur
    int*   relcur  = bcnt + 392;
    int*   offsets = (int*)alloc((size_t)(N + 1) * 4);
    float* dinv    = (float*)alloc((size_t)N * 4);
    unsigned* pairbuf = (unsigned*)alloc((size_t)E * 4);        // packed 32-bit
    int*   scol    = (int*)alloc((size_t)(E + 1) * 4);          // +1 sentinel
    __half* hp     = (__half*)alloc((size_t)(N + 1) * 64 * 2);  // +1 zero row
    float2* h2p    = (float2*)alloc((size_t)N * 8);

    const int nTile = (E + 4095) / 4096;  // 391

    hipMemsetAsync(bcnt, 0, 784 * 4, stream);   // bcnt + relcur, exact block
    k_bucketcount<<<nTile, 256, 0, stream>>>(row, bcnt, hp, E, nb, N);
    k_bin<<<nTile, 256, 0, stream>>>(row, col, bcnt, relcur, pairbuf, E, nb);
    k_sortnode<<<nb, 256, 0, stream>>>(pairbuf, bcnt, scol, offsets, dinv, N, E);
    k_gemm1<<<512, 256, 0, stream>>>(x, W1, dinv, hp, N);
    const int nwaves = (N + 7) / 8;                  // 8 nodes per wave
    k_agg1<<<(nwaves + 3) / 4, 256, 0, stream>>>(hp, offsets, scol, dinv, b1, W2, h2p, N, E);
    k_agg2<<<(N * 16 + 255) / 256, 256, 0, stream>>>(h2p, offsets, scol, dinv, b2, out, N);
}